// Round 3
// baseline (1027.937 us; speedup 1.0000x reference)
//
#include <hip/hip_runtime.h>
#include <hip/hip_bf16.h>
#include <math.h>

#define D_MODEL 1024
#define N_HEADS 16
#define HEAD_DIM 64
#define FF_DIM 4096
#define BATCH 2
#define SEQ 2048
#define ROWS (BATCH*SEQ)  // 4096

typedef __hip_bfloat16 bf16;
typedef short bf16x8 __attribute__((ext_vector_type(8)));
typedef float f32x4 __attribute__((ext_vector_type(4)));

__device__ __forceinline__ float bf2f(bf16 x) { return __bfloat162float(x); }
__device__ __forceinline__ bf16 f2bf(float x) { return __float2bfloat16(x); }

// ---------------- LayerNorm: f32 in -> bf16 out (one block per row) ----------------
__global__ __launch_bounds__(256) void ln_kernel(
    const float* __restrict__ x, const float* __restrict__ gamma,
    const float* __restrict__ beta, bf16* __restrict__ out)
{
    const int row = blockIdx.x;
    const int t = threadIdx.x;
    const float* xr = x + (size_t)row * D_MODEL;
    const float4 xv = *(const float4*)(xr + t * 4);
    float s  = xv.x + xv.y + xv.z + xv.w;
    float ss = xv.x * xv.x + xv.y * xv.y + xv.z * xv.z + xv.w * xv.w;
    #pragma unroll
    for (int o = 32; o > 0; o >>= 1) {
        s  += __shfl_down(s, o);
        ss += __shfl_down(ss, o);
    }
    __shared__ float ps[4], pss[4];
    const int w = t >> 6;
    if ((t & 63) == 0) { ps[w] = s; pss[w] = ss; }
    __syncthreads();
    if (t == 0) {
        ps[0]  = ps[0] + ps[1] + ps[2] + ps[3];
        pss[0] = pss[0] + pss[1] + pss[2] + pss[3];
    }
    __syncthreads();
    s = ps[0]; ss = pss[0];
    const float mu = s * (1.f / D_MODEL);
    float var = ss * (1.f / D_MODEL) - mu * mu;
    var = var < 0.f ? 0.f : var;
    const float rinv = rsqrtf(var + 1e-5f);
    const float4 gv = *(const float4*)(gamma + t * 4);
    const float4 bv = *(const float4*)(beta + t * 4);
    bf16* orow = out + (size_t)row * D_MODEL + t * 4;
    orow[0] = f2bf((xv.x - mu) * rinv * gv.x + bv.x);
    orow[1] = f2bf((xv.y - mu) * rinv * gv.y + bv.y);
    orow[2] = f2bf((xv.z - mu) * rinv * gv.z + bv.z);
    orow[3] = f2bf((xv.w - mu) * rinv * gv.w + bv.w);
}

// ------- GEMM: C[M,N] = A[M,K](bf16) @ W[N,K](f32->bf16)^T + bias(f32), epilogue -------
#define EPI_BIAS 0
#define EPI_GELU 1
#define EPI_RES  2

__device__ __forceinline__ bf16x8 cvt8(float a, float b, float c, float d,
                                       float e, float f, float g, float h) {
    union { bf16 s[8]; bf16x8 v; } u;
    u.s[0] = f2bf(a); u.s[1] = f2bf(b); u.s[2] = f2bf(c); u.s[3] = f2bf(d);
    u.s[4] = f2bf(e); u.s[5] = f2bf(f); u.s[6] = f2bf(g); u.s[7] = f2bf(h);
    return u.v;
}

template <int EPI, typename CT>
__global__ __launch_bounds__(256, 2) void gemm_nt(
    const bf16* __restrict__ A, const float* __restrict__ W,
    const float* __restrict__ bias, const float* __restrict__ res,
    CT* __restrict__ C, int M, int N, int K)
{
    __shared__ bf16 As[128 * 32];
    __shared__ bf16 Ws[128 * 32];
    const int tid  = threadIdx.x;
    const int wave = tid >> 6;
    const int lane = tid & 63;
    const int mBlock = blockIdx.y * 128;
    const int nBlock = blockIdx.x * 128;

    // staging map: thread t covers rows r0 and r0+64 at k-cols [c0, c0+8)
    const int r0 = tid >> 2;          // 0..63
    const int c0 = (tid & 3) * 8;     // 0,8,16,24
    const bf16*  aP0 = A + (size_t)(mBlock + r0) * K + c0;
    const bf16*  aP1 = A + (size_t)(mBlock + 64 + r0) * K + c0;
    const float* wP0 = W + (size_t)(nBlock + r0) * K + c0;
    const float* wP1 = W + (size_t)(nBlock + 64 + r0) * K + c0;

    const int wm = (wave >> 1) * 64;   // wave row offset in 128-tile
    const int wn = (wave & 1) * 64;    // wave col offset
    const int fRow = lane & 15;
    const int fK   = (lane >> 4) * 8;

    f32x4 acc[4][4];
    #pragma unroll
    for (int i = 0; i < 4; ++i)
        #pragma unroll
        for (int j = 0; j < 4; ++j) {
            f32x4 z = {0.f, 0.f, 0.f, 0.f};
            acc[i][j] = z;
        }

    for (int k0 = 0; k0 < K; k0 += 32) {
        const bf16x8 a0 = *(const bf16x8*)(aP0 + k0);
        const bf16x8 a1 = *(const bf16x8*)(aP1 + k0);
        const float4 wa0 = *(const float4*)(wP0 + k0);
        const float4 wa1 = *(const float4*)(wP0 + k0 + 4);
        const float4 wb0 = *(const float4*)(wP1 + k0);
        const float4 wb1 = *(const float4*)(wP1 + k0 + 4);
        const bf16x8 w0 = cvt8(wa0.x, wa0.y, wa0.z, wa0.w, wa1.x, wa1.y, wa1.z, wa1.w);
        const bf16x8 w1 = cvt8(wb0.x, wb0.y, wb0.z, wb0.w, wb1.x, wb1.y, wb1.z, wb1.w);
        __syncthreads();  // previous iteration's LDS reads complete
        *(bf16x8*)&As[r0 * 32 + c0]        = a0;
        *(bf16x8*)&As[(64 + r0) * 32 + c0] = a1;
        *(bf16x8*)&Ws[r0 * 32 + c0]        = w0;
        *(bf16x8*)&Ws[(64 + r0) * 32 + c0] = w1;
        __syncthreads();

        bf16x8 af[4], wf[4];
        #pragma unroll
        for (int ti = 0; ti < 4; ++ti)
            af[ti] = *(const bf16x8*)&As[(wm + ti * 16 + fRow) * 32 + fK];
        #pragma unroll
        for (int tj = 0; tj < 4; ++tj)
            wf[tj] = *(const bf16x8*)&Ws[(wn + tj * 16 + fRow) * 32 + fK];
        #pragma unroll
        for (int ti = 0; ti < 4; ++ti)
            #pragma unroll
            for (int tj = 0; tj < 4; ++tj)
                acc[ti][tj] = __builtin_amdgcn_mfma_f32_16x16x32_bf16(
                    af[ti], wf[tj], acc[ti][tj], 0, 0, 0);
    }

    const int lr = (lane >> 4) * 4;
    const int lc = lane & 15;
    #pragma unroll
    for (int ti = 0; ti < 4; ++ti) {
        #pragma unroll
        for (int tj = 0; tj < 4; ++tj) {
            const int n = nBlock + wn + tj * 16 + lc;
            const float bv = bias[n];
            #pragma unroll
            for (int rr = 0; rr < 4; ++rr) {
                const int m = mBlock + wm + ti * 16 + lr + rr;
                float vv = acc[ti][tj][rr] + bv;
                if (EPI == EPI_GELU)
                    vv = 0.5f * vv * (1.f + erff(vv * 0.70710678118654752f));
                if (EPI == EPI_RES)
                    vv += res[(size_t)m * N + n];
                if constexpr (sizeof(CT) == 2)
                    C[(size_t)m * N + n] = f2bf(vv);
                else
                    C[(size_t)m * N + n] = vv;
            }
        }
    }
}

// ---------------- Flash attention (correctness-first, vector FP32) ----------------
// grid: (B*N_HEADS, SEQ/32); block 256. Causal. bf16 q,k,v,ctx.
__global__ __launch_bounds__(256) void attn_kernel(
    const bf16* __restrict__ q, const bf16* __restrict__ k,
    const bf16* __restrict__ v, bf16* __restrict__ ctx)
{
    const int bh = blockIdx.x;
    const int qb = blockIdx.y;
    const int b = bh >> 4;
    const int h = bh & 15;
    const int tid = threadIdx.x;

    __shared__ float Qs[32][68];
    __shared__ float Ks[32][68];
    __shared__ float Vs[32][68];
    __shared__ float Sc[32][33];
    __shared__ float rowM[32], rowL[32], rowA[32];

    const int r  = tid >> 3;  // 0..31
    const int cc = tid & 7;   // 0..7

    {
        const size_t base = ((size_t)(b * SEQ + qb * 32 + r)) * D_MODEL + h * HEAD_DIM + cc * 8;
        #pragma unroll
        for (int i = 0; i < 8; ++i)
            Qs[r][cc * 8 + i] = bf2f(q[base + i]) * 0.125f;  // 1/sqrt(64)
    }
    if (tid < 32) { rowM[tid] = -INFINITY; rowL[tid] = 0.f; }

    float acc[8];
    #pragma unroll
    for (int i = 0; i < 8; ++i) acc[i] = 0.f;

    for (int kb = 0; kb <= qb; ++kb) {
        const int j0 = kb * 32;
        {
            const size_t base = ((size_t)(b * SEQ + j0 + r)) * D_MODEL + h * HEAD_DIM + cc * 8;
            #pragma unroll
            for (int i = 0; i < 8; ++i) Ks[r][cc * 8 + i] = bf2f(k[base + i]);
            #pragma unroll
            for (int i = 0; i < 8; ++i) Vs[r][cc * 8 + i] = bf2f(v[base + i]);
        }
        __syncthreads();
        {
            float s0 = 0.f, s1 = 0.f, s2 = 0.f, s3 = 0.f;
            #pragma unroll
            for (int d = 0; d < HEAD_DIM; d += 4) {
                const float4 qv = *(const float4*)&Qs[r][d];
                const float4 ka = *(const float4*)&Ks[cc][d];
                const float4 kb2 = *(const float4*)&Ks[cc + 8][d];
                const float4 kc = *(const float4*)&Ks[cc + 16][d];
                const float4 kd = *(const float4*)&Ks[cc + 24][d];
                s0 = fmaf(qv.x, ka.x, fmaf(qv.y, ka.y, fmaf(qv.z, ka.z, fmaf(qv.w, ka.w, s0))));
                s1 = fmaf(qv.x, kb2.x, fmaf(qv.y, kb2.y, fmaf(qv.z, kb2.z, fmaf(qv.w, kb2.w, s1))));
                s2 = fmaf(qv.x, kc.x, fmaf(qv.y, kc.y, fmaf(qv.z, kc.z, fmaf(qv.w, kc.w, s2))));
                s3 = fmaf(qv.x, kd.x, fmaf(qv.y, kd.y, fmaf(qv.z, kd.z, fmaf(qv.w, kd.w, s3))));
            }
            const int ig = qb * 32 + r;
            Sc[r][cc]      = (j0 + cc      <= ig) ? s0 : -INFINITY;
            Sc[r][cc + 8]  = (j0 + cc + 8  <= ig) ? s1 : -INFINITY;
            Sc[r][cc + 16] = (j0 + cc + 16 <= ig) ? s2 : -INFINITY;
            Sc[r][cc + 24] = (j0 + cc + 24 <= ig) ? s3 : -INFINITY;
        }
        __syncthreads();
        if (tid < 32) {
            float m = rowM[tid];
            float mx = m;
            #pragma unroll
            for (int c = 0; c < 32; ++c) mx = fmaxf(mx, Sc[tid][c]);
            const float al = expf(m - mx);
            float sum = 0.f;
            #pragma unroll
            for (int c = 0; c < 32; ++c) {
                const float p = expf(Sc[tid][c] - mx);
                Sc[tid][c] = p;
                sum += p;
            }
            rowM[tid] = mx;
            rowL[tid] = rowL[tid] * al + sum;
            rowA[tid] = al;
        }
        __syncthreads();
        {
            const float al = rowA[r];
            #pragma unroll
            for (int i = 0; i < 8; ++i) acc[i] *= al;
            for (int c = 0; c < 32; ++c) {
                const float p = Sc[r][c];
                const float4 v0 = *(const float4*)&Vs[c][cc * 8];
                const float4 v1 = *(const float4*)&Vs[c][cc * 8 + 4];
                acc[0] += p * v0.x; acc[1] += p * v0.y;
                acc[2] += p * v0.z; acc[3] += p * v0.w;
                acc[4] += p * v1.x; acc[5] += p * v1.y;
                acc[6] += p * v1.z; acc[7] += p * v1.w;
            }
        }
        __syncthreads();
    }

    const float inv = 1.f / rowL[r];
    const size_t obase = ((size_t)(b * SEQ + qb * 32 + r)) * D_MODEL + h * HEAD_DIM + cc * 8;
    #pragma unroll
    for (int i = 0; i < 8; ++i) ctx[obase + i] = f2bf(acc[i] * inv);
}

extern "C" void kernel_launch(void* const* d_in, const int* in_sizes, int n_in,
                              void* d_out, int out_size, void* d_ws, size_t ws_size,
                              hipStream_t stream) {
    // All float tensors are float32 per the reference (jnp.float32).
    const float* x   = (const float*)d_in[0];
    // d_in[1] = attn_mask (int32, causal tril) -- handled analytically
    const float* Wq  = (const float*)d_in[2];
    const float* bq  = (const float*)d_in[3];
    const float* Wk  = (const float*)d_in[4];
    const float* bk  = (const float*)d_in[5];
    const float* Wv  = (const float*)d_in[6];
    const float* bv  = (const float*)d_in[7];
    const float* Wo  = (const float*)d_in[8];
    const float* bo  = (const float*)d_in[9];
    const float* W1  = (const float*)d_in[10];
    const float* b1  = (const float*)d_in[11];
    const float* W2  = (const float*)d_in[12];
    const float* b2  = (const float*)d_in[13];
    const float* g1  = (const float*)d_in[14];
    const float* be1 = (const float*)d_in[15];
    const float* g2  = (const float*)d_in[16];
    const float* be2 = (const float*)d_in[17];
    float* out = (float*)d_out;

    // Workspace (bf16 intermediates, 40 MB):
    const size_t MB = 1024 * 1024;
    char* ws = (char*)d_ws;
    bf16* xn1 = (bf16*)(ws);             //  0.. 8MB (reused as xn2)
    bf16* qB  = (bf16*)(ws + 8 * MB);    //  8..16MB
    bf16* kB  = (bf16*)(ws + 16 * MB);   // 16..24MB
    bf16* vB  = (bf16*)(ws + 24 * MB);   // 24..32MB
    bf16* ctx = (bf16*)(ws + 32 * MB);   // 32..40MB
    bf16* hB  = (bf16*)(ws + 8 * MB);    //  8..40MB (reuses q/k/v/ctx after they die)
    bf16* xn2 = xn1;
    float* x2 = out;                     // attn residual output lives in d_out (f32)

    // 1) LN1 (f32 -> bf16)
    ln_kernel<<<ROWS, 256, 0, stream>>>(x, g1, be1, xn1);
    // 2) Q,K,V projections (bf16 A, f32 W, bf16 C)
    gemm_nt<EPI_BIAS, bf16><<<dim3(D_MODEL / 128, ROWS / 128), 256, 0, stream>>>(
        xn1, Wq, bq, nullptr, qB, ROWS, D_MODEL, D_MODEL);
    gemm_nt<EPI_BIAS, bf16><<<dim3(D_MODEL / 128, ROWS / 128), 256, 0, stream>>>(
        xn1, Wk, bk, nullptr, kB, ROWS, D_MODEL, D_MODEL);
    gemm_nt<EPI_BIAS, bf16><<<dim3(D_MODEL / 128, ROWS / 128), 256, 0, stream>>>(
        xn1, Wv, bv, nullptr, vB, ROWS, D_MODEL, D_MODEL);
    // 3) attention (bf16)
    attn_kernel<<<dim3(BATCH * N_HEADS, SEQ / 32), 256, 0, stream>>>(qB, kB, vB, ctx);
    // 4) O projection + residual (f32 out -> d_out)
    gemm_nt<EPI_RES, float><<<dim3(D_MODEL / 128, ROWS / 128), 256, 0, stream>>>(
        ctx, Wo, bo, x, x2, ROWS, D_MODEL, D_MODEL);
    // 5) LN2 (f32 d_out -> bf16)
    ln_kernel<<<ROWS, 256, 0, stream>>>(x2, g2, be2, xn2);
    // 6) FFN1 + exact gelu (bf16 C)
    gemm_nt<EPI_GELU, bf16><<<dim3(FF_DIM / 128, ROWS / 128), 256, 0, stream>>>(
        xn2, W1, b1, nullptr, hB, ROWS, FF_DIM, D_MODEL);
    // 7) FFN2 + residual (res == C == d_out: same-thread same-address, safe)
    gemm_nt<EPI_RES, float><<<dim3(D_MODEL / 128, ROWS / 128), 256, 0, stream>>>(
        hB, W2, b2, x2, out, ROWS, D_MODEL, FF_DIM);
}

// Round 4
// 567.927 us; speedup vs baseline: 1.8100x; 1.8100x over previous
//
#include <hip/hip_runtime.h>
#include <hip/hip_bf16.h>
#include <math.h>

#define D_MODEL 1024
#define N_HEADS 16
#define HEAD_DIM 64
#define FF_DIM 4096
#define BATCH 2
#define SEQ 2048
#define ROWS (BATCH*SEQ)  // 4096

typedef __hip_bfloat16 bf16;
typedef short bf16x8 __attribute__((ext_vector_type(8)));
typedef short bf16x4 __attribute__((ext_vector_type(4)));
typedef float f32x4 __attribute__((ext_vector_type(4)));

__device__ __forceinline__ float bf2f(bf16 x) { return __bfloat162float(x); }
__device__ __forceinline__ bf16 f2bf(float x) { return __float2bfloat16(x); }

// ---------------- LayerNorm: f32 in -> bf16 out (one block per row) ----------------
__global__ __launch_bounds__(256) void ln_kernel(
    const float* __restrict__ x, const float* __restrict__ gamma,
    const float* __restrict__ beta, bf16* __restrict__ out)
{
    const int row = blockIdx.x;
    const int t = threadIdx.x;
    const float* xr = x + (size_t)row * D_MODEL;
    const float4 xv = *(const float4*)(xr + t * 4);
    float s  = xv.x + xv.y + xv.z + xv.w;
    float ss = xv.x * xv.x + xv.y * xv.y + xv.z * xv.z + xv.w * xv.w;
    #pragma unroll
    for (int o = 32; o > 0; o >>= 1) {
        s  += __shfl_down(s, o);
        ss += __shfl_down(ss, o);
    }
    __shared__ float ps[4], pss[4];
    const int w = t >> 6;
    if ((t & 63) == 0) { ps[w] = s; pss[w] = ss; }
    __syncthreads();
    if (t == 0) {
        ps[0]  = ps[0] + ps[1] + ps[2] + ps[3];
        pss[0] = pss[0] + pss[1] + pss[2] + pss[3];
    }
    __syncthreads();
    s = ps[0]; ss = pss[0];
    const float mu = s * (1.f / D_MODEL);
    float var = ss * (1.f / D_MODEL) - mu * mu;
    var = var < 0.f ? 0.f : var;
    const float rinv = rsqrtf(var + 1e-5f);
    const float4 gv = *(const float4*)(gamma + t * 4);
    const float4 bv = *(const float4*)(beta + t * 4);
    bf16* orow = out + (size_t)row * D_MODEL + t * 4;
    orow[0] = f2bf((xv.x - mu) * rinv * gv.x + bv.x);
    orow[1] = f2bf((xv.y - mu) * rinv * gv.y + bv.y);
    orow[2] = f2bf((xv.z - mu) * rinv * gv.z + bv.z);
    orow[3] = f2bf((xv.w - mu) * rinv * gv.w + bv.w);
}

// ------- GEMM: C[M,N] = A[M,K](bf16) @ W[N,K](f32->bf16)^T + bias(f32), epilogue -------
#define EPI_BIAS 0
#define EPI_GELU 1
#define EPI_RES  2

__device__ __forceinline__ bf16x8 cvt8(float a, float b, float c, float d,
                                       float e, float f, float g, float h) {
    union { bf16 s[8]; bf16x8 v; } u;
    u.s[0] = f2bf(a); u.s[1] = f2bf(b); u.s[2] = f2bf(c); u.s[3] = f2bf(d);
    u.s[4] = f2bf(e); u.s[5] = f2bf(f); u.s[6] = f2bf(g); u.s[7] = f2bf(h);
    return u.v;
}

template <int EPI, typename CT>
__global__ __launch_bounds__(256, 2) void gemm_nt(
    const bf16* __restrict__ A, const float* __restrict__ W,
    const float* __restrict__ bias, const float* __restrict__ res,
    CT* __restrict__ C, int M, int N, int K)
{
    __shared__ bf16 As[128 * 32];
    __shared__ bf16 Ws[128 * 32];
    const int tid  = threadIdx.x;
    const int wave = tid >> 6;
    const int lane = tid & 63;
    const int mBlock = blockIdx.y * 128;
    const int nBlock = blockIdx.x * 128;

    const int r0 = tid >> 2;          // 0..63
    const int c0 = (tid & 3) * 8;     // 0,8,16,24
    const bf16*  aP0 = A + (size_t)(mBlock + r0) * K + c0;
    const bf16*  aP1 = A + (size_t)(mBlock + 64 + r0) * K + c0;
    const float* wP0 = W + (size_t)(nBlock + r0) * K + c0;
    const float* wP1 = W + (size_t)(nBlock + 64 + r0) * K + c0;

    const int wm = (wave >> 1) * 64;
    const int wn = (wave & 1) * 64;
    const int fRow = lane & 15;
    const int fK   = (lane >> 4) * 8;

    f32x4 acc[4][4];
    #pragma unroll
    for (int i = 0; i < 4; ++i)
        #pragma unroll
        for (int j = 0; j < 4; ++j) {
            f32x4 z = {0.f, 0.f, 0.f, 0.f};
            acc[i][j] = z;
        }

    for (int k0 = 0; k0 < K; k0 += 32) {
        const bf16x8 a0 = *(const bf16x8*)(aP0 + k0);
        const bf16x8 a1 = *(const bf16x8*)(aP1 + k0);
        const float4 wa0 = *(const float4*)(wP0 + k0);
        const float4 wa1 = *(const float4*)(wP0 + k0 + 4);
        const float4 wb0 = *(const float4*)(wP1 + k0);
        const float4 wb1 = *(const float4*)(wP1 + k0 + 4);
        const bf16x8 w0 = cvt8(wa0.x, wa0.y, wa0.z, wa0.w, wa1.x, wa1.y, wa1.z, wa1.w);
        const bf16x8 w1 = cvt8(wb0.x, wb0.y, wb0.z, wb0.w, wb1.x, wb1.y, wb1.z, wb1.w);
        __syncthreads();
        *(bf16x8*)&As[r0 * 32 + c0]        = a0;
        *(bf16x8*)&As[(64 + r0) * 32 + c0] = a1;
        *(bf16x8*)&Ws[r0 * 32 + c0]        = w0;
        *(bf16x8*)&Ws[(64 + r0) * 32 + c0] = w1;
        __syncthreads();

        bf16x8 af[4], wf[4];
        #pragma unroll
        for (int ti = 0; ti < 4; ++ti)
            af[ti] = *(const bf16x8*)&As[(wm + ti * 16 + fRow) * 32 + fK];
        #pragma unroll
        for (int tj = 0; tj < 4; ++tj)
            wf[tj] = *(const bf16x8*)&Ws[(wn + tj * 16 + fRow) * 32 + fK];
        #pragma unroll
        for (int ti = 0; ti < 4; ++ti)
            #pragma unroll
            for (int tj = 0; tj < 4; ++tj)
                acc[ti][tj] = __builtin_amdgcn_mfma_f32_16x16x32_bf16(
                    af[ti], wf[tj], acc[ti][tj], 0, 0, 0);
    }

    const int lr = (lane >> 4) * 4;
    const int lc = lane & 15;
    #pragma unroll
    for (int ti = 0; ti < 4; ++ti) {
        #pragma unroll
        for (int tj = 0; tj < 4; ++tj) {
            const int n = nBlock + wn + tj * 16 + lc;
            const float bv = bias[n];
            #pragma unroll
            for (int rr = 0; rr < 4; ++rr) {
                const int m = mBlock + wm + ti * 16 + lr + rr;
                float vv = acc[ti][tj][rr] + bv;
                if (EPI == EPI_GELU)
                    vv = 0.5f * vv * (1.f + erff(vv * 0.70710678118654752f));
                if (EPI == EPI_RES)
                    vv += res[(size_t)m * N + n];
                if constexpr (sizeof(CT) == 2)
                    C[(size_t)m * N + n] = f2bf(vv);
                else
                    C[(size_t)m * N + n] = vv;
            }
        }
    }
}

// ---------------- MFMA flash attention ----------------
// grid (B*N_HEADS, SEQ/64), block 256 = 4 waves; wave w owns Q rows [qb*64+w*16, +16).
// K-tiles of 32 keys staged in LDS; causal; online softmax per quarter-wave.
__global__ __launch_bounds__(256) void attn_mfma(
    const bf16* __restrict__ q, const bf16* __restrict__ k,
    const bf16* __restrict__ v, bf16* __restrict__ ctx)
{
    const int bh = blockIdx.x;
    const int b = bh >> 4, h = bh & 15;
    const int qb = (gridDim.y - 1) - blockIdx.y;  // descending: big blocks first
    const int tid = threadIdx.x;
    const int wave = tid >> 6, lane = tid & 63;
    const int fm = lane & 15;       // A/B frag row, D col
    const int fq = lane >> 4;       // quad: frag k-chunk, D row group

    __shared__ bf16 Ks[2][32][32];  // [k-half][key][k%32] -> 64B rows, conflict-free b128
    __shared__ bf16 Vts[64][32];    // [d][key]            -> 64B rows
    __shared__ bf16 Ps[4][16][32];  // per-wave P (C-layout -> A-layout round trip)

    const int q0 = qb * 64 + wave * 16;
    const size_t qrow = ((size_t)(b * SEQ) + q0 + fm) * D_MODEL + h * HEAD_DIM;
    const bf16x8 Qf0 = *(const bf16x8*)&q[qrow + fq * 8];        // k = 0..31
    const bf16x8 Qf1 = *(const bf16x8*)&q[qrow + 32 + fq * 8];   // k = 32..63

    f32x4 o[4];
    #pragma unroll
    for (int i = 0; i < 4; ++i) { f32x4 z = {0.f,0.f,0.f,0.f}; o[i] = z; }
    float m_r[4] = {-INFINITY, -INFINITY, -INFINITY, -INFINITY};
    float l_r[4] = {0.f, 0.f, 0.f, 0.f};

    // staging maps (all 256 threads)
    const int sr = tid >> 3;      // K: key row 0..31
    const int sc = tid & 7;       // K: 8-elem chunk 0..7
    const int vrp = tid & 15;     // V: key pair 0..15 (keys 2vrp, 2vrp+1)
    const int vdg = tid >> 4;     // V: d group 0..15 (d = vdg*4 .. +3)

    const int nKB = 2 * qb + 2;   // causal extent for this 64-row block
    for (int kb = 0; kb < nKB; ++kb) {
        const int j0 = kb * 32;
        const size_t kbase = ((size_t)(b * SEQ) + j0 + sr) * D_MODEL + h * HEAD_DIM + sc * 8;
        const bf16x8 kv = *(const bf16x8*)&k[kbase];
        const size_t vbase = ((size_t)(b * SEQ) + j0 + 2 * vrp) * D_MODEL + h * HEAD_DIM + vdg * 4;
        const bf16x4 va = *(const bf16x4*)&v[vbase];
        const bf16x4 vb = *(const bf16x4*)&v[vbase + D_MODEL];
        __syncthreads();   // previous iteration's LDS reads done
        *(bf16x8*)&Ks[sc >> 2][sr][(sc & 3) * 8] = kv;
        #pragma unroll
        for (int i = 0; i < 4; ++i) {
            const unsigned packed = (unsigned)(unsigned short)va[i] |
                                    ((unsigned)(unsigned short)vb[i] << 16);
            *(unsigned*)&Vts[vdg * 4 + i][2 * vrp] = packed;
        }
        __syncthreads();

        // --- S = Q K^T (two 16-key subtiles) ---
        float sc0[2][4];
        #pragma unroll
        for (int sub = 0; sub < 2; ++sub) {
            const int n0 = sub * 16;
            const bf16x8 kf0 = *(const bf16x8*)&Ks[0][n0 + fm][fq * 8];
            const bf16x8 kf1 = *(const bf16x8*)&Ks[1][n0 + fm][fq * 8];
            f32x4 acc = {0.f, 0.f, 0.f, 0.f};
            acc = __builtin_amdgcn_mfma_f32_16x16x32_bf16(Qf0, kf0, acc, 0, 0, 0);
            acc = __builtin_amdgcn_mfma_f32_16x16x32_bf16(Qf1, kf1, acc, 0, 0, 0);
            #pragma unroll
            for (int reg = 0; reg < 4; ++reg) {
                const int qi = q0 + fq * 4 + reg;
                float sv = acc[reg] * 0.125f;     // 1/sqrt(64)
                if (j0 + n0 + fm > qi) sv = -INFINITY;
                sc0[sub][reg] = sv;
            }
        }

        // --- online softmax (row = quarter-wave of 16 lanes) ---
        #pragma unroll
        for (int reg = 0; reg < 4; ++reg) {
            float mx = fmaxf(sc0[0][reg], sc0[1][reg]);
            #pragma unroll
            for (int off = 1; off < 16; off <<= 1)
                mx = fmaxf(mx, __shfl_xor(mx, off));
            const float mnew = fmaxf(m_r[reg], mx);
            const float p0 = __expf(sc0[0][reg] - mnew);
            const float p1 = __expf(sc0[1][reg] - mnew);
            float sum = p0 + p1;
            #pragma unroll
            for (int off = 1; off < 16; off <<= 1)
                sum += __shfl_xor(sum, off);
            const float alpha = __expf(m_r[reg] - mnew);
            m_r[reg] = mnew;
            l_r[reg] = l_r[reg] * alpha + sum;
            #pragma unroll
            for (int dn = 0; dn < 4; ++dn) o[dn][reg] *= alpha;
            Ps[wave][fq * 4 + reg][fm]      = f2bf(p0);
            Ps[wave][fq * 4 + reg][16 + fm] = f2bf(p1);
        }

        // --- O += P V (K-dim = 32 keys, one MFMA per 16-d subtile) ---
        const bf16x8 pf = *(const bf16x8*)&Ps[wave][fm][fq * 8];
        #pragma unroll
        for (int dn = 0; dn < 4; ++dn) {
            const bf16x8 vf = *(const bf16x8*)&Vts[dn * 16 + fm][fq * 8];
            o[dn] = __builtin_amdgcn_mfma_f32_16x16x32_bf16(pf, vf, o[dn], 0, 0, 0);
        }
    }

    #pragma unroll
    for (int reg = 0; reg < 4; ++reg) {
        const float inv = 1.f / l_r[reg];
        const size_t obase = ((size_t)(b * SEQ) + q0 + fq * 4 + reg) * D_MODEL + h * HEAD_DIM;
        #pragma unroll
        for (int dn = 0; dn < 4; ++dn)
            ctx[obase + dn * 16 + fm] = f2bf(o[dn][reg] * inv);
    }
}

extern "C" void kernel_launch(void* const* d_in, const int* in_sizes, int n_in,
                              void* d_out, int out_size, void* d_ws, size_t ws_size,
                              hipStream_t stream) {
    const float* x   = (const float*)d_in[0];
    // d_in[1] = attn_mask (int32, causal tril) -- handled analytically
    const float* Wq  = (const float*)d_in[2];
    const float* bq  = (const float*)d_in[3];
    const float* Wk  = (const float*)d_in[4];
    const float* bk  = (const float*)d_in[5];
    const float* Wv  = (const float*)d_in[6];
    const float* bv  = (const float*)d_in[7];
    const float* Wo  = (const float*)d_in[8];
    const float* bo  = (const float*)d_in[9];
    const float* W1  = (const float*)d_in[10];
    const float* b1  = (const float*)d_in[11];
    const float* W2  = (const float*)d_in[12];
    const float* b2  = (const float*)d_in[13];
    const float* g1  = (const float*)d_in[14];
    const float* be1 = (const float*)d_in[15];
    const float* g2  = (const float*)d_in[16];
    const float* be2 = (const float*)d_in[17];
    float* out = (float*)d_out;

    const size_t MB = 1024 * 1024;
    char* ws = (char*)d_ws;
    bf16* xn1 = (bf16*)(ws);             //  0.. 8MB (reused as xn2)
    bf16* qB  = (bf16*)(ws + 8 * MB);    //  8..16MB
    bf16* kB  = (bf16*)(ws + 16 * MB);   // 16..24MB
    bf16* vB  = (bf16*)(ws + 24 * MB);   // 24..32MB
    bf16* ctx = (bf16*)(ws + 32 * MB);   // 32..40MB
    bf16* hB  = (bf16*)(ws + 8 * MB);    //  8..40MB (reuses q/k/v/ctx)
    bf16* xn2 = xn1;
    float* x2 = out;

    ln_kernel<<<ROWS, 256, 0, stream>>>(x, g1, be1, xn1);
    gemm_nt<EPI_BIAS, bf16><<<dim3(D_MODEL / 128, ROWS / 128), 256, 0, stream>>>(
        xn1, Wq, bq, nullptr, qB, ROWS, D_MODEL, D_MODEL);
    gemm_nt<EPI_BIAS, bf16><<<dim3(D_MODEL / 128, ROWS / 128), 256, 0, stream>>>(
        xn1, Wk, bk, nullptr, kB, ROWS, D_MODEL, D_MODEL);
    gemm_nt<EPI_BIAS, bf16><<<dim3(D_MODEL / 128, ROWS / 128), 256, 0, stream>>>(
        xn1, Wv, bv, nullptr, vB, ROWS, D_MODEL, D_MODEL);
    attn_mfma<<<dim3(BATCH * N_HEADS, SEQ / 64), 256, 0, stream>>>(qB, kB, vB, ctx);
    gemm_nt<EPI_RES, float><<<dim3(D_MODEL / 128, ROWS / 128), 256, 0, stream>>>(
        ctx, Wo, bo, x, x2, ROWS, D_MODEL, D_MODEL);
    ln_kernel<<<ROWS, 256, 0, stream>>>(x2, g2, be2, xn2);
    gemm_nt<EPI_GELU, bf16><<<dim3(FF_DIM / 128, ROWS / 128), 256, 0, stream>>>(
        xn2, W1, b1, nullptr, hB, ROWS, FF_DIM, D_MODEL);
    gemm_nt<EPI_RES, float><<<dim3(D_MODEL / 128, ROWS / 128), 256, 0, stream>>>(
        hB, W2, b2, x2, out, ROWS, D_MODEL, FF_DIM);
}

// Round 5
// 489.460 us; speedup vs baseline: 2.1001x; 1.1603x over previous
//
#include <hip/hip_runtime.h>
#include <hip/hip_bf16.h>
#include <math.h>

#define D_MODEL 1024
#define N_HEADS 16
#define HEAD_DIM 64
#define FF_DIM 4096
#define BATCH 2
#define SEQ 2048
#define ROWS (BATCH*SEQ)  // 4096

typedef __hip_bfloat16 bf16;
typedef short bf16x8 __attribute__((ext_vector_type(8)));
typedef short bf16x4 __attribute__((ext_vector_type(4)));
typedef float f32x4 __attribute__((ext_vector_type(4)));

__device__ __forceinline__ float bf2f(bf16 x) { return __bfloat162float(x); }
__device__ __forceinline__ bf16 f2bf(float x) { return __float2bfloat16(x); }

// async 16B/lane global->LDS; LDS dest must be wave-uniform base, lane i lands at base + i*16B
__device__ __forceinline__ void glds16(const bf16* g, bf16* l) {
    __builtin_amdgcn_global_load_lds(
        (const __attribute__((address_space(1))) void*)g,
        (__attribute__((address_space(3))) void*)l,
        16, 0, 0);
}

// ---------------- f32 -> bf16 weight conversion ----------------
__global__ __launch_bounds__(256) void cvt_kernel(
    const float* __restrict__ src, bf16* __restrict__ dst, int n)
{
    const int i = (blockIdx.x * 256 + threadIdx.x) * 8;
    if (i >= n) return;
    const float4 a = *(const float4*)(src + i);
    const float4 b = *(const float4*)(src + i + 4);
    union { bf16 s[8]; bf16x8 v; } u;
    u.s[0] = f2bf(a.x); u.s[1] = f2bf(a.y); u.s[2] = f2bf(a.z); u.s[3] = f2bf(a.w);
    u.s[4] = f2bf(b.x); u.s[5] = f2bf(b.y); u.s[6] = f2bf(b.z); u.s[7] = f2bf(b.w);
    *(bf16x8*)(dst + i) = u.v;
}

// ---------------- LayerNorm: f32 in -> bf16 out (one block per row) ----------------
__global__ __launch_bounds__(256) void ln_kernel(
    const float* __restrict__ x, const float* __restrict__ gamma,
    const float* __restrict__ beta, bf16* __restrict__ out)
{
    const int row = blockIdx.x;
    const int t = threadIdx.x;
    const float* xr = x + (size_t)row * D_MODEL;
    const float4 xv = *(const float4*)(xr + t * 4);
    float s  = xv.x + xv.y + xv.z + xv.w;
    float ss = xv.x * xv.x + xv.y * xv.y + xv.z * xv.z + xv.w * xv.w;
    #pragma unroll
    for (int o = 32; o > 0; o >>= 1) {
        s  += __shfl_down(s, o);
        ss += __shfl_down(ss, o);
    }
    __shared__ float ps[4], pss[4];
    const int w = t >> 6;
    if ((t & 63) == 0) { ps[w] = s; pss[w] = ss; }
    __syncthreads();
    if (t == 0) {
        ps[0]  = ps[0] + ps[1] + ps[2] + ps[3];
        pss[0] = pss[0] + pss[1] + pss[2] + pss[3];
    }
    __syncthreads();
    s = ps[0]; ss = pss[0];
    const float mu = s * (1.f / D_MODEL);
    float var = ss * (1.f / D_MODEL) - mu * mu;
    var = var < 0.f ? 0.f : var;
    const float rinv = rsqrtf(var + 1e-5f);
    const float4 gv = *(const float4*)(gamma + t * 4);
    const float4 bv = *(const float4*)(beta + t * 4);
    bf16* orow = out + (size_t)row * D_MODEL + t * 4;
    orow[0] = f2bf((xv.x - mu) * rinv * gv.x + bv.x);
    orow[1] = f2bf((xv.y - mu) * rinv * gv.y + bv.y);
    orow[2] = f2bf((xv.z - mu) * rinv * gv.z + bv.z);
    orow[3] = f2bf((xv.w - mu) * rinv * gv.w + bv.w);
}

#define EPI_BIAS 0
#define EPI_GELU 1
#define EPI_RES  2

// ------- bf16 GEMM (fast path): C[M,N] = A[M,K] @ Wb[N,K]^T + bias, epilogue -------
// 128 x TN tile, BK=32, global_load_lds 16B staging (m97 structure).
template <int EPI, int TN, typename CT>
__global__ __launch_bounds__(256) void gemm_bb(
    const bf16* __restrict__ A, const bf16* __restrict__ W,
    const float* __restrict__ bias, const float* __restrict__ res,
    CT* __restrict__ C, int M, int N, int K)
{
    __shared__ bf16 As[128 * 32];
    __shared__ bf16 Ws[TN * 32];
    const int tid  = threadIdx.x;
    const int wave = tid >> 6;
    const int lane = tid & 63;
    const int mBlock = blockIdx.y * 128;
    const int nBlock = blockIdx.x * TN;

    // staging: lane L of a wave -> row base + L/4, k-col (L&3)*8 (dst byte = L*16)
    const int sK = (lane & 3) * 8;
    const int aRow = wave * 32 + (lane >> 2);
    const bf16* aSrc0 = A + (size_t)(mBlock + aRow) * K + sK;
    const bf16* aSrc1 = aSrc0 + (size_t)16 * K;
    bf16* aDst0 = &As[(wave * 32) * 32];
    bf16* aDst1 = &As[(wave * 32 + 16) * 32];

    const int wRow = (TN == 128) ? (wave * 32 + (lane >> 2)) : (wave * 16 + (lane >> 2));
    const bf16* wSrc0 = W + (size_t)(nBlock + wRow) * K + sK;
    const bf16* wSrc1 = wSrc0 + (size_t)16 * K;   // used only when TN==128
    bf16* wDst0 = (TN == 128) ? &Ws[(wave * 32) * 32] : &Ws[(wave * 16) * 32];
    bf16* wDst1 = &Ws[(wave * 32 + 16) * 32];

    constexpr int WN = (TN == 128) ? 64 : 32;  // per-wave N extent
    constexpr int NJ = WN / 16;
    const int wm = (wave >> 1) * 64;
    const int wn = (wave & 1) * WN;
    const int fRow = lane & 15;
    const int fK   = (lane >> 4) * 8;

    f32x4 acc[4][NJ];
    #pragma unroll
    for (int i = 0; i < 4; ++i)
        #pragma unroll
        for (int j = 0; j < NJ; ++j) {
            f32x4 z = {0.f, 0.f, 0.f, 0.f};
            acc[i][j] = z;
        }

    for (int k0 = 0; k0 < K; k0 += 32) {
        glds16(aSrc0, aDst0);
        glds16(aSrc1, aDst1);
        glds16(wSrc0, wDst0);
        if (TN == 128) glds16(wSrc1, wDst1);
        aSrc0 += 32; aSrc1 += 32; wSrc0 += 32; wSrc1 += 32;
        __syncthreads();   // drains vmcnt (DMA complete) + barrier

        bf16x8 af[4], wf[NJ];
        #pragma unroll
        for (int ti = 0; ti < 4; ++ti)
            af[ti] = *(const bf16x8*)&As[(wm + ti * 16 + fRow) * 32 + fK];
        #pragma unroll
        for (int tj = 0; tj < NJ; ++tj)
            wf[tj] = *(const bf16x8*)&Ws[(wn + tj * 16 + fRow) * 32 + fK];
        #pragma unroll
        for (int ti = 0; ti < 4; ++ti)
            #pragma unroll
            for (int tj = 0; tj < NJ; ++tj)
                acc[ti][tj] = __builtin_amdgcn_mfma_f32_16x16x32_bf16(
                    af[ti], wf[tj], acc[ti][tj], 0, 0, 0);
        __syncthreads();   // LDS reads done before next tile's DMA overwrites
    }

    const int lr = (lane >> 4) * 4;
    const int lc = lane & 15;
    #pragma unroll
    for (int ti = 0; ti < 4; ++ti) {
        #pragma unroll
        for (int tj = 0; tj < NJ; ++tj) {
            const int n = nBlock + wn + tj * 16 + lc;
            const float bv = bias[n];
            #pragma unroll
            for (int rr = 0; rr < 4; ++rr) {
                const int m = mBlock + wm + ti * 16 + lr + rr;
                float vv = acc[ti][tj][rr] + bv;
                if (EPI == EPI_GELU)
                    vv = 0.5f * vv * (1.f + erff(vv * 0.70710678118654752f));
                if (EPI == EPI_RES)
                    vv += res[(size_t)m * N + n];
                if constexpr (sizeof(CT) == 2)
                    C[(size_t)m * N + n] = f2bf(vv);
                else
                    C[(size_t)m * N + n] = vv;
            }
        }
    }
}

// ------- f32-weight GEMM (fallback path, round-3 proven) -------
__device__ __forceinline__ bf16x8 cvt8(float a, float b, float c, float d,
                                       float e, float f, float g, float h) {
    union { bf16 s[8]; bf16x8 v; } u;
    u.s[0] = f2bf(a); u.s[1] = f2bf(b); u.s[2] = f2bf(c); u.s[3] = f2bf(d);
    u.s[4] = f2bf(e); u.s[5] = f2bf(f); u.s[6] = f2bf(g); u.s[7] = f2bf(h);
    return u.v;
}

template <int EPI, typename CT>
__global__ __launch_bounds__(256, 2) void gemm_nt(
    const bf16* __restrict__ A, const float* __restrict__ W,
    const float* __restrict__ bias, const float* __restrict__ res,
    CT* __restrict__ C, int M, int N, int K)
{
    __shared__ bf16 As[128 * 32];
    __shared__ bf16 Ws[128 * 32];
    const int tid  = threadIdx.x;
    const int wave = tid >> 6;
    const int lane = tid & 63;
    const int mBlock = blockIdx.y * 128;
    const int nBlock = blockIdx.x * 128;

    const int r0 = tid >> 2;
    const int c0 = (tid & 3) * 8;
    const bf16*  aP0 = A + (size_t)(mBlock + r0) * K + c0;
    const bf16*  aP1 = A + (size_t)(mBlock + 64 + r0) * K + c0;
    const float* wP0 = W + (size_t)(nBlock + r0) * K + c0;
    const float* wP1 = W + (size_t)(nBlock + 64 + r0) * K + c0;

    const int wm = (wave >> 1) * 64;
    const int wn = (wave & 1) * 64;
    const int fRow = lane & 15;
    const int fK   = (lane >> 4) * 8;

    f32x4 acc[4][4];
    #pragma unroll
    for (int i = 0; i < 4; ++i)
        #pragma unroll
        for (int j = 0; j < 4; ++j) {
            f32x4 z = {0.f, 0.f, 0.f, 0.f};
            acc[i][j] = z;
        }

    for (int k0 = 0; k0 < K; k0 += 32) {
        const bf16x8 a0 = *(const bf16x8*)(aP0 + k0);
        const bf16x8 a1 = *(const bf16x8*)(aP1 + k0);
        const float4 wa0 = *(const float4*)(wP0 + k0);
        const float4 wa1 = *(const float4*)(wP0 + k0 + 4);
        const float4 wb0 = *(const float4*)(wP1 + k0);
        const float4 wb1 = *(const float4*)(wP1 + k0 + 4);
        const bf16x8 w0 = cvt8(wa0.x, wa0.y, wa0.z, wa0.w, wa1.x, wa1.y, wa1.z, wa1.w);
        const bf16x8 w1 = cvt8(wb0.x, wb0.y, wb0.z, wb0.w, wb1.x, wb1.y, wb1.z, wb1.w);
        __syncthreads();
        *(bf16x8*)&As[r0 * 32 + c0]        = a0;
        *(bf16x8*)&As[(64 + r0) * 32 + c0] = a1;
        *(bf16x8*)&Ws[r0 * 32 + c0]        = w0;
        *(bf16x8*)&Ws[(64 + r0) * 32 + c0] = w1;
        __syncthreads();

        bf16x8 af[4], wf[4];
        #pragma unroll
        for (int ti = 0; ti < 4; ++ti)
            af[ti] = *(const bf16x8*)&As[(wm + ti * 16 + fRow) * 32 + fK];
        #pragma unroll
        for (int tj = 0; tj < 4; ++tj)
            wf[tj] = *(const bf16x8*)&Ws[(wn + tj * 16 + fRow) * 32 + fK];
        #pragma unroll
        for (int ti = 0; ti < 4; ++ti)
            #pragma unroll
            for (int tj = 0; tj < 4; ++tj)
                acc[ti][tj] = __builtin_amdgcn_mfma_f32_16x16x32_bf16(
                    af[ti], wf[tj], acc[ti][tj], 0, 0, 0);
    }

    const int lr = (lane >> 4) * 4;
    const int lc = lane & 15;
    #pragma unroll
    for (int ti = 0; ti < 4; ++ti) {
        #pragma unroll
        for (int tj = 0; tj < 4; ++tj) {
            const int n = nBlock + wn + tj * 16 + lc;
            const float bv = bias[n];
            #pragma unroll
            for (int rr = 0; rr < 4; ++rr) {
                const int m = mBlock + wm + ti * 16 + lr + rr;
                float vv = acc[ti][tj][rr] + bv;
                if (EPI == EPI_GELU)
                    vv = 0.5f * vv * (1.f + erff(vv * 0.70710678118654752f));
                if (EPI == EPI_RES)
                    vv += res[(size_t)m * N + n];
                if constexpr (sizeof(CT) == 2)
                    C[(size_t)m * N + n] = f2bf(vv);
                else
                    C[(size_t)m * N + n] = vv;
            }
        }
    }
}

// ---------------- MFMA flash attention (round-3, unchanged) ----------------
__global__ __launch_bounds__(256) void attn_mfma(
    const bf16* __restrict__ q, const bf16* __restrict__ k,
    const bf16* __restrict__ v, bf16* __restrict__ ctx)
{
    const int bh = blockIdx.x;
    const int b = bh >> 4, h = bh & 15;
    const int qb = (gridDim.y - 1) - blockIdx.y;
    const int tid = threadIdx.x;
    const int wave = tid >> 6, lane = tid & 63;
    const int fm = lane & 15;
    const int fq = lane >> 4;

    __shared__ bf16 Ks[2][32][32];
    __shared__ bf16 Vts[64][32];
    __shared__ bf16 Ps[4][16][32];

    const int q0 = qb * 64 + wave * 16;
    const size_t qrow = ((size_t)(b * SEQ) + q0 + fm) * D_MODEL + h * HEAD_DIM;
    const bf16x8 Qf0 = *(const bf16x8*)&q[qrow + fq * 8];
    const bf16x8 Qf1 = *(const bf16x8*)&q[qrow + 32 + fq * 8];

    f32x4 o[4];
    #pragma unroll
    for (int i = 0; i < 4; ++i) { f32x4 z = {0.f,0.f,0.f,0.f}; o[i] = z; }
    float m_r[4] = {-INFINITY, -INFINITY, -INFINITY, -INFINITY};
    float l_r[4] = {0.f, 0.f, 0.f, 0.f};

    const int sr = tid >> 3;
    const int sc = tid & 7;
    const int vrp = tid & 15;
    const int vdg = tid >> 4;

    const int nKB = 2 * qb + 2;
    for (int kb = 0; kb < nKB; ++kb) {
        const int j0 = kb * 32;
        const size_t kbase = ((size_t)(b * SEQ) + j0 + sr) * D_MODEL + h * HEAD_DIM + sc * 8;
        const bf16x8 kv = *(const bf16x8*)&k[kbase];
        const size_t vbase = ((size_t)(b * SEQ) + j0 + 2 * vrp) * D_MODEL + h * HEAD_DIM + vdg * 4;
        const bf16x4 va = *(const bf16x4*)&v[vbase];
        const bf16x4 vb = *(const bf16x4*)&v[vbase + D_MODEL];
        __syncthreads();
        *(bf16x8*)&Ks[sc >> 2][sr][(sc & 3) * 8] = kv;
        #pragma unroll
        for (int i = 0; i < 4; ++i) {
            const unsigned packed = (unsigned)(unsigned short)va[i] |
                                    ((unsigned)(unsigned short)vb[i] << 16);
            *(unsigned*)&Vts[vdg * 4 + i][2 * vrp] = packed;
        }
        __syncthreads();

        float sc0[2][4];
        #pragma unroll
        for (int sub = 0; sub < 2; ++sub) {
            const int n0 = sub * 16;
            const bf16x8 kf0 = *(const bf16x8*)&Ks[0][n0 + fm][fq * 8];
            const bf16x8 kf1 = *(const bf16x8*)&Ks[1][n0 + fm][fq * 8];
            f32x4 acc = {0.f, 0.f, 0.f, 0.f};
            acc = __builtin_amdgcn_mfma_f32_16x16x32_bf16(Qf0, kf0, acc, 0, 0, 0);
            acc = __builtin_amdgcn_mfma_f32_16x16x32_bf16(Qf1, kf1, acc, 0, 0, 0);
            #pragma unroll
            for (int reg = 0; reg < 4; ++reg) {
                const int qi = q0 + fq * 4 + reg;
                float sv = acc[reg] * 0.125f;
                if (j0 + n0 + fm > qi) sv = -INFINITY;
                sc0[sub][reg] = sv;
            }
        }

        #pragma unroll
        for (int reg = 0; reg < 4; ++reg) {
            float mx = fmaxf(sc0[0][reg], sc0[1][reg]);
            #pragma unroll
            for (int off = 1; off < 16; off <<= 1)
                mx = fmaxf(mx, __shfl_xor(mx, off));
            const float mnew = fmaxf(m_r[reg], mx);
            const float p0 = __expf(sc0[0][reg] - mnew);
            const float p1 = __expf(sc0[1][reg] - mnew);
            float sum = p0 + p1;
            #pragma unroll
            for (int off = 1; off < 16; off <<= 1)
                sum += __shfl_xor(sum, off);
            const float alpha = __expf(m_r[reg] - mnew);
            m_r[reg] = mnew;
            l_r[reg] = l_r[reg] * alpha + sum;
            #pragma unroll
            for (int dn = 0; dn < 4; ++dn) o[dn][reg] *= alpha;
            Ps[wave][fq * 4 + reg][fm]      = f2bf(p0);
            Ps[wave][fq * 4 + reg][16 + fm] = f2bf(p1);
        }

        const bf16x8 pf = *(const bf16x8*)&Ps[wave][fm][fq * 8];
        #pragma unroll
        for (int dn = 0; dn < 4; ++dn) {
            const bf16x8 vf = *(const bf16x8*)&Vts[dn * 16 + fm][fq * 8];
            o[dn] = __builtin_amdgcn_mfma_f32_16x16x32_bf16(pf, vf, o[dn], 0, 0, 0);
        }
    }

    #pragma unroll
    for (int reg = 0; reg < 4; ++reg) {
        const float inv = 1.f / l_r[reg];
        const size_t obase = ((size_t)(b * SEQ) + q0 + fq * 4 + reg) * D_MODEL + h * HEAD_DIM;
        #pragma unroll
        for (int dn = 0; dn < 4; ++dn)
            ctx[obase + dn * 16 + fm] = f2bf(o[dn][reg] * inv);
    }
}

extern "C" void kernel_launch(void* const* d_in, const int* in_sizes, int n_in,
                              void* d_out, int out_size, void* d_ws, size_t ws_size,
                              hipStream_t stream) {
    const float* x   = (const float*)d_in[0];
    // d_in[1] = attn_mask (int32, causal tril) -- handled analytically
    const float* Wq  = (const float*)d_in[2];
    const float* bq  = (const float*)d_in[3];
    const float* Wk  = (const float*)d_in[4];
    const float* bk  = (const float*)d_in[5];
    const float* Wv  = (const float*)d_in[6];
    const float* bv  = (const float*)d_in[7];
    const float* Wo  = (const float*)d_in[8];
    const float* bo  = (const float*)d_in[9];
    const float* W1  = (const float*)d_in[10];
    const float* b1  = (const float*)d_in[11];
    const float* W2  = (const float*)d_in[12];
    const float* b2  = (const float*)d_in[13];
    const float* g1  = (const float*)d_in[14];
    const float* be1 = (const float*)d_in[15];
    const float* g2  = (const float*)d_in[16];
    const float* be2 = (const float*)d_in[17];
    float* out = (float*)d_out;

    const size_t MB = 1024 * 1024;
    char* ws = (char*)d_ws;
    bf16* xn1 = (bf16*)(ws);             //  0.. 8MB (reused as xn2)
    bf16* qB  = (bf16*)(ws + 8 * MB);    //  8..16MB
    bf16* kB  = (bf16*)(ws + 16 * MB);   // 16..24MB
    bf16* vB  = (bf16*)(ws + 24 * MB);   // 24..32MB
    bf16* ctx = (bf16*)(ws + 32 * MB);   // 32..40MB
    bf16* hB  = (bf16*)(ws + 8 * MB);    //  8..40MB (reuses q/k/v/ctx)
    bf16* xn2 = xn1;
    float* x2 = out;

    ln_kernel<<<ROWS, 256, 0, stream>>>(x, g1, be1, xn1);

    if (ws_size >= 64 * MB) {
        // ---- fast path: bf16 weights + global_load_lds GEMMs ----
        bf16* wqb = (bf16*)(ws + 40 * MB);   // 40..42MB
        bf16* wkb = (bf16*)(ws + 42 * MB);   // 42..44MB
        bf16* wvb = (bf16*)(ws + 44 * MB);   // 44..46MB
        bf16* wob = (bf16*)(ws + 46 * MB);   // 46..48MB
        bf16* w1b = (bf16*)(ws + 48 * MB);   // 48..56MB
        bf16* w2b = (bf16*)(ws + 56 * MB);   // 56..64MB
        const int nD = D_MODEL * D_MODEL;    // 1M
        const int nF = D_MODEL * FF_DIM;     // 4M
        cvt_kernel<<<nD / 2048, 256, 0, stream>>>(Wq, wqb, nD);
        cvt_kernel<<<nD / 2048, 256, 0, stream>>>(Wk, wkb, nD);
        cvt_kernel<<<nD / 2048, 256, 0, stream>>>(Wv, wvb, nD);
        cvt_kernel<<<nD / 2048, 256, 0, stream>>>(Wo, wob, nD);
        cvt_kernel<<<nF / 2048, 256, 0, stream>>>(W1, w1b, nF);
        cvt_kernel<<<nF / 2048, 256, 0, stream>>>(W2, w2b, nF);

        gemm_bb<EPI_BIAS, 64, bf16><<<dim3(D_MODEL / 64, ROWS / 128), 256, 0, stream>>>(
            xn1, wqb, bq, nullptr, qB, ROWS, D_MODEL, D_MODEL);
        gemm_bb<EPI_BIAS, 64, bf16><<<dim3(D_MODEL / 64, ROWS / 128), 256, 0, stream>>>(
            xn1, wkb, bk, nullptr, kB, ROWS, D_MODEL, D_MODEL);
        gemm_bb<EPI_BIAS, 64, bf16><<<dim3(D_MODEL / 64, ROWS / 128), 256, 0, stream>>>(
            xn1, wvb, bv, nullptr, vB, ROWS, D_MODEL, D_MODEL);
        attn_mfma<<<dim3(BATCH * N_HEADS, SEQ / 64), 256, 0, stream>>>(qB, kB, vB, ctx);
        gemm_bb<EPI_RES, 64, float><<<dim3(D_MODEL / 64, ROWS / 128), 256, 0, stream>>>(
            ctx, wob, bo, x, x2, ROWS, D_MODEL, D_MODEL);
        ln_kernel<<<ROWS, 256, 0, stream>>>(x2, g2, be2, xn2);
        gemm_bb<EPI_GELU, 128, bf16><<<dim3(FF_DIM / 128, ROWS / 128), 256, 0, stream>>>(
            xn2, w1b, b1, nullptr, hB, ROWS, FF_DIM, D_MODEL);
        gemm_bb<EPI_RES, 64, float><<<dim3(D_MODEL / 64, ROWS / 128), 256, 0, stream>>>(
            hB, w2b, b2, x2, out, ROWS, D_MODEL, FF_DIM);
    } else {
        // ---- fallback: round-3 proven path (f32 weights, register staging) ----
        gemm_nt<EPI_BIAS, bf16><<<dim3(D_MODEL / 128, ROWS / 128), 256, 0, stream>>>(
            xn1, Wq, bq, nullptr, qB, ROWS, D_MODEL, D_MODEL);
        gemm_nt<EPI_BIAS, bf16><<<dim3(D_MODEL / 128, ROWS / 128), 256, 0, stream>>>(
            xn1, Wk, bk, nullptr, kB, ROWS, D_MODEL, D_MODEL);
        gemm_nt<EPI_BIAS, bf16><<<dim3(D_MODEL / 128, ROWS / 128), 256, 0, stream>>>(
            xn1, Wv, bv, nullptr, vB, ROWS, D_MODEL, D_MODEL);
        attn_mfma<<<dim3(BATCH * N_HEADS, SEQ / 64), 256, 0, stream>>>(qB, kB, vB, ctx);
        gemm_nt<EPI_RES, float><<<dim3(D_MODEL / 128, ROWS / 128), 256, 0, stream>>>(
            ctx, Wo, bo, x, x2, ROWS, D_MODEL, D_MODEL);
        ln_kernel<<<ROWS, 256, 0, stream>>>(x2, g2, be2, xn2);
        gemm_nt<EPI_GELU, bf16><<<dim3(FF_DIM / 128, ROWS / 128), 256, 0, stream>>>(
            xn2, W1, b1, nullptr, hB, ROWS, FF_DIM, D_MODEL);
        gemm_nt<EPI_RES, float><<<dim3(D_MODEL / 128, ROWS / 128), 256, 0, stream>>>(
            hB, W2, b2, x2, out, ROWS, D_MODEL, FF_DIM);
    }
}

// Round 6
// 450.865 us; speedup vs baseline: 2.2799x; 1.0856x over previous
//
#include <hip/hip_runtime.h>
#include <hip/hip_bf16.h>
#include <math.h>

#define D_MODEL 1024
#define N_HEADS 16
#define HEAD_DIM 64
#define FF_DIM 4096
#define BATCH 2
#define SEQ 2048
#define ROWS (BATCH*SEQ)  // 4096

typedef __hip_bfloat16 bf16;
typedef short bf16x8 __attribute__((ext_vector_type(8)));
typedef short bf16x4 __attribute__((ext_vector_type(4)));
typedef float f32x4 __attribute__((ext_vector_type(4)));

__device__ __forceinline__ float bf2f(bf16 x) { return __bfloat162float(x); }
__device__ __forceinline__ bf16 f2bf(float x) { return __float2bfloat16(x); }

// async 16B/lane global->LDS; LDS dest is wave-uniform base, lane i lands at base + i*16B
__device__ __forceinline__ void glds16(const bf16* g, bf16* l) {
    __builtin_amdgcn_global_load_lds(
        (const __attribute__((address_space(1))) void*)g,
        (__attribute__((address_space(3))) void*)l,
        16, 0, 0);
}

// ---------------- f32 -> bf16 weight conversion ----------------
__global__ __launch_bounds__(256) void cvt_kernel(
    const float* __restrict__ src, bf16* __restrict__ dst, int n)
{
    const int i = (blockIdx.x * 256 + threadIdx.x) * 8;
    if (i >= n) return;
    const float4 a = *(const float4*)(src + i);
    const float4 b = *(const float4*)(src + i + 4);
    union { bf16 s[8]; bf16x8 v; } u;
    u.s[0] = f2bf(a.x); u.s[1] = f2bf(a.y); u.s[2] = f2bf(a.z); u.s[3] = f2bf(a.w);
    u.s[4] = f2bf(b.x); u.s[5] = f2bf(b.y); u.s[6] = f2bf(b.z); u.s[7] = f2bf(b.w);
    *(bf16x8*)(dst + i) = u.v;
}

// ---------------- LayerNorm: f32 in -> bf16 out (one block per row) ----------------
__global__ __launch_bounds__(256) void ln_kernel(
    const float* __restrict__ x, const float* __restrict__ gamma,
    const float* __restrict__ beta, bf16* __restrict__ out)
{
    const int row = blockIdx.x;
    const int t = threadIdx.x;
    const float* xr = x + (size_t)row * D_MODEL;
    const float4 xv = *(const float4*)(xr + t * 4);
    float s  = xv.x + xv.y + xv.z + xv.w;
    float ss = xv.x * xv.x + xv.y * xv.y + xv.z * xv.z + xv.w * xv.w;
    #pragma unroll
    for (int o = 32; o > 0; o >>= 1) {
        s  += __shfl_down(s, o);
        ss += __shfl_down(ss, o);
    }
    __shared__ float ps[4], pss[4];
    const int w = t >> 6;
    if ((t & 63) == 0) { ps[w] = s; pss[w] = ss; }
    __syncthreads();
    if (t == 0) {
        ps[0]  = ps[0] + ps[1] + ps[2] + ps[3];
        pss[0] = pss[0] + pss[1] + pss[2] + pss[3];
    }
    __syncthreads();
    s = ps[0]; ss = pss[0];
    const float mu = s * (1.f / D_MODEL);
    float var = ss * (1.f / D_MODEL) - mu * mu;
    var = var < 0.f ? 0.f : var;
    const float rinv = rsqrtf(var + 1e-5f);
    const float4 gv = *(const float4*)(gamma + t * 4);
    const float4 bv = *(const float4*)(beta + t * 4);
    bf16* orow = out + (size_t)row * D_MODEL + t * 4;
    orow[0] = f2bf((xv.x - mu) * rinv * gv.x + bv.x);
    orow[1] = f2bf((xv.y - mu) * rinv * gv.y + bv.y);
    orow[2] = f2bf((xv.z - mu) * rinv * gv.z + bv.z);
    orow[3] = f2bf((xv.w - mu) * rinv * gv.w + bv.w);
}

#define EPI_BIAS 0
#define EPI_GELU 1
#define EPI_RES  2

// ------- bf16 GEMM: C[M,N] = A[M,K] @ Wb[N,K]^T + bias, epilogue -------
template <int EPI, int TN, typename CT>
__global__ __launch_bounds__(256) void gemm_bb(
    const bf16* __restrict__ A, const bf16* __restrict__ W,
    const float* __restrict__ bias, const float* __restrict__ res,
    CT* __restrict__ C, int M, int N, int K)
{
    __shared__ bf16 As[128 * 32];
    __shared__ bf16 Ws[TN * 32];
    const int tid  = threadIdx.x;
    const int wave = tid >> 6;
    const int lane = tid & 63;
    const int mBlock = blockIdx.y * 128;
    const int nBlock = blockIdx.x * TN;

    const int sK = (lane & 3) * 8;
    const int aRow = wave * 32 + (lane >> 2);
    const bf16* aSrc0 = A + (size_t)(mBlock + aRow) * K + sK;
    const bf16* aSrc1 = aSrc0 + (size_t)16 * K;
    bf16* aDst0 = &As[(wave * 32) * 32];
    bf16* aDst1 = &As[(wave * 32 + 16) * 32];

    const int wRow = (TN == 128) ? (wave * 32 + (lane >> 2)) : (wave * 16 + (lane >> 2));
    const bf16* wSrc0 = W + (size_t)(nBlock + wRow) * K + sK;
    const bf16* wSrc1 = wSrc0 + (size_t)16 * K;
    bf16* wDst0 = (TN == 128) ? &Ws[(wave * 32) * 32] : &Ws[(wave * 16) * 32];
    bf16* wDst1 = &Ws[(wave * 32 + 16) * 32];

    constexpr int WN = (TN == 128) ? 64 : 32;
    constexpr int NJ = WN / 16;
    const int wm = (wave >> 1) * 64;
    const int wn = (wave & 1) * WN;
    const int fRow = lane & 15;
    const int fK   = (lane >> 4) * 8;

    f32x4 acc[4][NJ];
    #pragma unroll
    for (int i = 0; i < 4; ++i)
        #pragma unroll
        for (int j = 0; j < NJ; ++j) {
            f32x4 z = {0.f, 0.f, 0.f, 0.f};
            acc[i][j] = z;
        }

    for (int k0 = 0; k0 < K; k0 += 32) {
        glds16(aSrc0, aDst0);
        glds16(aSrc1, aDst1);
        glds16(wSrc0, wDst0);
        if (TN == 128) glds16(wSrc1, wDst1);
        aSrc0 += 32; aSrc1 += 32; wSrc0 += 32; wSrc1 += 32;
        __syncthreads();

        bf16x8 af[4], wf[NJ];
        #pragma unroll
        for (int ti = 0; ti < 4; ++ti)
            af[ti] = *(const bf16x8*)&As[(wm + ti * 16 + fRow) * 32 + fK];
        #pragma unroll
        for (int tj = 0; tj < NJ; ++tj)
            wf[tj] = *(const bf16x8*)&Ws[(wn + tj * 16 + fRow) * 32 + fK];
        #pragma unroll
        for (int ti = 0; ti < 4; ++ti)
            #pragma unroll
            for (int tj = 0; tj < NJ; ++tj)
                acc[ti][tj] = __builtin_amdgcn_mfma_f32_16x16x32_bf16(
                    af[ti], wf[tj], acc[ti][tj], 0, 0, 0);
        __syncthreads();
    }

    const int lr = (lane >> 4) * 4;
    const int lc = lane & 15;
    #pragma unroll
    for (int ti = 0; ti < 4; ++ti) {
        #pragma unroll
        for (int tj = 0; tj < NJ; ++tj) {
            const int n = nBlock + wn + tj * 16 + lc;
            const float bv = bias[n];
            #pragma unroll
            for (int rr = 0; rr < 4; ++rr) {
                const int m = mBlock + wm + ti * 16 + lr + rr;
                float vv = acc[ti][tj][rr] + bv;
                if (EPI == EPI_GELU)
                    vv = 0.5f * vv * (1.f + erff(vv * 0.70710678118654752f));
                if (EPI == EPI_RES)
                    vv += res[(size_t)m * N + n];
                if constexpr (sizeof(CT) == 2)
                    C[(size_t)m * N + n] = f2bf(vv);
                else
                    C[(size_t)m * N + n] = vv;
            }
        }
    }
}

// ------- fused QKV GEMM: C[4096,3072] = xn @ [Wq;Wk;Wv]^T + [bq;bk;bv] -------
__global__ __launch_bounds__(256) void gemm_qkv(
    const bf16* __restrict__ A, const bf16* __restrict__ W,
    const float* __restrict__ bq, const float* __restrict__ bk,
    const float* __restrict__ bv, bf16* __restrict__ C)
{
    constexpr int K = D_MODEL, N = 3 * D_MODEL;
    __shared__ bf16 As[128 * 32];
    __shared__ bf16 Ws[64 * 32];
    const int tid  = threadIdx.x;
    const int wave = tid >> 6;
    const int lane = tid & 63;
    const int mBlock = blockIdx.y * 128;
    const int nBlock = blockIdx.x * 64;
    const int seg = nBlock >> 10;                       // 0=q,1=k,2=v (block-uniform)
    const float* bias = (seg == 0) ? bq : (seg == 1) ? bk : bv;

    const int sK = (lane & 3) * 8;
    const int aRow = wave * 32 + (lane >> 2);
    const bf16* aSrc0 = A + (size_t)(mBlock + aRow) * K + sK;
    const bf16* aSrc1 = aSrc0 + (size_t)16 * K;
    bf16* aDst0 = &As[(wave * 32) * 32];
    bf16* aDst1 = &As[(wave * 32 + 16) * 32];
    const int wRow = wave * 16 + (lane >> 2);
    const bf16* wSrc0 = W + (size_t)(nBlock + wRow) * K + sK;
    bf16* wDst0 = &Ws[(wave * 16) * 32];

    const int wm = (wave >> 1) * 64;
    const int wn = (wave & 1) * 32;
    const int fRow = lane & 15;
    const int fK   = (lane >> 4) * 8;

    f32x4 acc[4][2];
    #pragma unroll
    for (int i = 0; i < 4; ++i)
        #pragma unroll
        for (int j = 0; j < 2; ++j) {
            f32x4 z = {0.f, 0.f, 0.f, 0.f};
            acc[i][j] = z;
        }

    for (int k0 = 0; k0 < K; k0 += 32) {
        glds16(aSrc0, aDst0);
        glds16(aSrc1, aDst1);
        glds16(wSrc0, wDst0);
        aSrc0 += 32; aSrc1 += 32; wSrc0 += 32;
        __syncthreads();
        bf16x8 af[4], wf[2];
        #pragma unroll
        for (int ti = 0; ti < 4; ++ti)
            af[ti] = *(const bf16x8*)&As[(wm + ti * 16 + fRow) * 32 + fK];
        #pragma unroll
        for (int tj = 0; tj < 2; ++tj)
            wf[tj] = *(const bf16x8*)&Ws[(wn + tj * 16 + fRow) * 32 + fK];
        #pragma unroll
        for (int ti = 0; ti < 4; ++ti)
            #pragma unroll
            for (int tj = 0; tj < 2; ++tj)
                acc[ti][tj] = __builtin_amdgcn_mfma_f32_16x16x32_bf16(
                    af[ti], wf[tj], acc[ti][tj], 0, 0, 0);
        __syncthreads();
    }

    const int lr = (lane >> 4) * 4;
    const int lc = lane & 15;
    #pragma unroll
    for (int ti = 0; ti < 4; ++ti) {
        #pragma unroll
        for (int tj = 0; tj < 2; ++tj) {
            const int n = nBlock + wn + tj * 16 + lc;
            const float bvv = bias[n & 1023];
            #pragma unroll
            for (int rr = 0; rr < 4; ++rr) {
                const int m = mBlock + wm + ti * 16 + lr + rr;
                C[(size_t)m * N + n] = f2bf(acc[ti][tj][rr] + bvv);
            }
        }
    }
}

// ------- f32-weight GEMM (fallback path) -------
__device__ __forceinline__ bf16x8 cvt8(float a, float b, float c, float d,
                                       float e, float f, float g, float h) {
    union { bf16 s[8]; bf16x8 v; } u;
    u.s[0] = f2bf(a); u.s[1] = f2bf(b); u.s[2] = f2bf(c); u.s[3] = f2bf(d);
    u.s[4] = f2bf(e); u.s[5] = f2bf(f); u.s[6] = f2bf(g); u.s[7] = f2bf(h);
    return u.v;
}

template <int EPI, typename CT>
__global__ __launch_bounds__(256, 2) void gemm_nt(
    const bf16* __restrict__ A, const float* __restrict__ W,
    const float* __restrict__ bias, const float* __restrict__ res,
    CT* __restrict__ C, int M, int N, int K)
{
    __shared__ bf16 As[128 * 32];
    __shared__ bf16 Ws[128 * 32];
    const int tid  = threadIdx.x;
    const int wave = tid >> 6;
    const int lane = tid & 63;
    const int mBlock = blockIdx.y * 128;
    const int nBlock = blockIdx.x * 128;
    const int r0 = tid >> 2;
    const int c0 = (tid & 3) * 8;
    const bf16*  aP0 = A + (size_t)(mBlock + r0) * K + c0;
    const bf16*  aP1 = A + (size_t)(mBlock + 64 + r0) * K + c0;
    const float* wP0 = W + (size_t)(nBlock + r0) * K + c0;
    const float* wP1 = W + (size_t)(nBlock + 64 + r0) * K + c0;
    const int wm = (wave >> 1) * 64;
    const int wn = (wave & 1) * 64;
    const int fRow = lane & 15;
    const int fK   = (lane >> 4) * 8;
    f32x4 acc[4][4];
    #pragma unroll
    for (int i = 0; i < 4; ++i)
        #pragma unroll
        for (int j = 0; j < 4; ++j) {
            f32x4 z = {0.f, 0.f, 0.f, 0.f};
            acc[i][j] = z;
        }
    for (int k0 = 0; k0 < K; k0 += 32) {
        const bf16x8 a0 = *(const bf16x8*)(aP0 + k0);
        const bf16x8 a1 = *(const bf16x8*)(aP1 + k0);
        const float4 wa0 = *(const float4*)(wP0 + k0);
        const float4 wa1 = *(const float4*)(wP0 + k0 + 4);
        const float4 wb0 = *(const float4*)(wP1 + k0);
        const float4 wb1 = *(const float4*)(wP1 + k0 + 4);
        const bf16x8 w0 = cvt8(wa0.x, wa0.y, wa0.z, wa0.w, wa1.x, wa1.y, wa1.z, wa1.w);
        const bf16x8 w1 = cvt8(wb0.x, wb0.y, wb0.z, wb0.w, wb1.x, wb1.y, wb1.z, wb1.w);
        __syncthreads();
        *(bf16x8*)&As[r0 * 32 + c0]        = a0;
        *(bf16x8*)&As[(64 + r0) * 32 + c0] = a1;
        *(bf16x8*)&Ws[r0 * 32 + c0]        = w0;
        *(bf16x8*)&Ws[(64 + r0) * 32 + c0] = w1;
        __syncthreads();
        bf16x8 af[4], wf[4];
        #pragma unroll
        for (int ti = 0; ti < 4; ++ti)
            af[ti] = *(const bf16x8*)&As[(wm + ti * 16 + fRow) * 32 + fK];
        #pragma unroll
        for (int tj = 0; tj < 4; ++tj)
            wf[tj] = *(const bf16x8*)&Ws[(wn + tj * 16 + fRow) * 32 + fK];
        #pragma unroll
        for (int ti = 0; ti < 4; ++ti)
            #pragma unroll
            for (int tj = 0; tj < 4; ++tj)
                acc[ti][tj] = __builtin_amdgcn_mfma_f32_16x16x32_bf16(
                    af[ti], wf[tj], acc[ti][tj], 0, 0, 0);
    }
    const int lr = (lane >> 4) * 4;
    const int lc = lane & 15;
    #pragma unroll
    for (int ti = 0; ti < 4; ++ti) {
        #pragma unroll
        for (int tj = 0; tj < 4; ++tj) {
            const int n = nBlock + wn + tj * 16 + lc;
            const float bv = bias[n];
            #pragma unroll
            for (int rr = 0; rr < 4; ++rr) {
                const int m = mBlock + wm + ti * 16 + lr + rr;
                float vv = acc[ti][tj][rr] + bv;
                if (EPI == EPI_GELU)
                    vv = 0.5f * vv * (1.f + erff(vv * 0.70710678118654752f));
                if (EPI == EPI_RES)
                    vv += res[(size_t)m * N + n];
                if constexpr (sizeof(CT) == 2)
                    C[(size_t)m * N + n] = f2bf(vv);
                else
                    C[(size_t)m * N + n] = vv;
            }
        }
    }
}

// ---------------- MFMA flash attention, S^T formulation ----------------
// grid (B*N_HEADS, SEQ/64), block 256 = 4 waves; wave w owns Q rows [qb*64+w*16, +16).
// S^T = K·Q^T puts q on lanes (col=fm) -> softmax is per-lane + 2 shfls across quads.
// O^T = V·P^T accumulates [d][q]; epilogue packs 4 consecutive d per store.
__global__ __launch_bounds__(256) void attn_mfma(
    const bf16* __restrict__ q, const bf16* __restrict__ k,
    const bf16* __restrict__ v, int qkvStride, bf16* __restrict__ ctx)
{
    const int bh = blockIdx.x;
    const int b = bh >> 4, h = bh & 15;
    const int qb = (gridDim.y - 1) - blockIdx.y;  // descending: big blocks first
    const int tid = threadIdx.x;
    const int wave = tid >> 6, lane = tid & 63;
    const int fm = lane & 15;       // col index (q); also A-frag row (key / d)
    const int fq = lane >> 4;       // quad

    __shared__ bf16 Ks[2][32][40];  // [k-half][key][k%32], rows padded to 80B
    __shared__ bf16 Vts[64][40];    // [d][key]
    __shared__ bf16 Ps[4][16][40];  // per-wave P^T round-trip: [q][key]

    const int q0 = qb * 64 + wave * 16;
    const size_t qrow = ((size_t)(b * SEQ) + q0 + fm) * qkvStride + h * HEAD_DIM;
    const bf16x8 Qf0 = *(const bf16x8*)&q[qrow + fq * 8];        // d 0..31
    const bf16x8 Qf1 = *(const bf16x8*)&q[qrow + 32 + fq * 8];   // d 32..63

    f32x4 o[4];   // o[dn][reg] = O^T[d = dn*16 + fq*4 + reg][q = q0+fm]
    #pragma unroll
    for (int i = 0; i < 4; ++i) { f32x4 z = {0.f,0.f,0.f,0.f}; o[i] = z; }
    float m_r = -INFINITY, l_r = 0.f;

    const int sr = tid >> 3;      // K staging: key row 0..31
    const int sc = tid & 7;       // K staging: 8-elem chunk
    const int vrp = tid & 15;     // V staging: key pair
    const int vdg = tid >> 4;     // V staging: d group

    const int nKB = 2 * qb + 2;
    for (int kb = 0; kb < nKB; ++kb) {
        const int j0 = kb * 32;
        const size_t kbase = ((size_t)(b * SEQ) + j0 + sr) * qkvStride + h * HEAD_DIM + sc * 8;
        const bf16x8 kv = *(const bf16x8*)&k[kbase];
        const size_t vbase = ((size_t)(b * SEQ) + j0 + 2 * vrp) * qkvStride + h * HEAD_DIM + vdg * 4;
        const bf16x4 va = *(const bf16x4*)&v[vbase];
        const bf16x4 vb = *(const bf16x4*)&v[vbase + qkvStride];
        __syncthreads();
        *(bf16x8*)&Ks[sc >> 2][sr][(sc & 3) * 8] = kv;
        #pragma unroll
        for (int i = 0; i < 4; ++i) {
            const unsigned packed = (unsigned)(unsigned short)va[i] |
                                    ((unsigned)(unsigned short)vb[i] << 16);
            *(unsigned*)&Vts[vdg * 4 + i][2 * vrp] = packed;
        }
        __syncthreads();

        if (j0 <= q0 + 15) {   // tile not fully masked for this wave
            // --- S^T = K·Q^T : rows=keys (fq*4+reg), cols=q (fm) ---
            float p[2][4];
            #pragma unroll
            for (int sub = 0; sub < 2; ++sub) {
                const int n0 = sub * 16;
                const bf16x8 kf0 = *(const bf16x8*)&Ks[0][n0 + fm][fq * 8];
                const bf16x8 kf1 = *(const bf16x8*)&Ks[1][n0 + fm][fq * 8];
                f32x4 acc = {0.f, 0.f, 0.f, 0.f};
                acc = __builtin_amdgcn_mfma_f32_16x16x32_bf16(kf0, Qf0, acc, 0, 0, 0);
                acc = __builtin_amdgcn_mfma_f32_16x16x32_bf16(kf1, Qf1, acc, 0, 0, 0);
                #pragma unroll
                for (int reg = 0; reg < 4; ++reg)
                    p[sub][reg] = acc[reg] * 0.125f;
                if (j0 + 31 > q0) {   // diagonal tile: apply causal mask
                    #pragma unroll
                    for (int reg = 0; reg < 4; ++reg)
                        if (j0 + n0 + fq * 4 + reg > q0 + fm) p[sub][reg] = -INFINITY;
                }
            }

            // --- online softmax, per lane (q = q0+fm) ---
            float mx = p[0][0];
            #pragma unroll
            for (int sub = 0; sub < 2; ++sub)
                #pragma unroll
                for (int reg = 0; reg < 4; ++reg) mx = fmaxf(mx, p[sub][reg]);
            mx = fmaxf(mx, __shfl_xor(mx, 16));
            mx = fmaxf(mx, __shfl_xor(mx, 32));
            const float mnew = fmaxf(m_r, mx);
            float sum = 0.f;
            #pragma unroll
            for (int sub = 0; sub < 2; ++sub)
                #pragma unroll
                for (int reg = 0; reg < 4; ++reg) {
                    const float e = __expf(p[sub][reg] - mnew);
                    p[sub][reg] = e;
                    sum += e;
                }
            sum += __shfl_xor(sum, 16);
            sum += __shfl_xor(sum, 32);
            const float alpha = __expf(m_r - mnew);
            m_r = mnew;
            l_r = l_r * alpha + sum;
            #pragma unroll
            for (int dn = 0; dn < 4; ++dn)
                #pragma unroll
                for (int rr = 0; rr < 4; ++rr) o[dn][rr] *= alpha;

            // write P^T: lane (fm,fq) holds keys {sub*16 + fq*4 + reg} for q=fm
            #pragma unroll
            for (int sub = 0; sub < 2; ++sub) {
                union { unsigned u; bf16 s[2]; } pk0, pk1;
                pk0.s[0] = f2bf(p[sub][0]); pk0.s[1] = f2bf(p[sub][1]);
                pk1.s[0] = f2bf(p[sub][2]); pk1.s[1] = f2bf(p[sub][3]);
                *(unsigned*)&Ps[wave][fm][sub * 16 + fq * 4]     = pk0.u;
                *(unsigned*)&Ps[wave][fm][sub * 16 + fq * 4 + 2] = pk1.u;
            }

            // --- O^T += V·P^T (K-dim = 32 keys) ---
            const bf16x8 pf = *(const bf16x8*)&Ps[wave][fm][fq * 8];
            #pragma unroll
            for (int dn = 0; dn < 4; ++dn) {
                const bf16x8 vf = *(const bf16x8*)&Vts[dn * 16 + fm][fq * 8];
                o[dn] = __builtin_amdgcn_mfma_f32_16x16x32_bf16(vf, pf, o[dn], 0, 0, 0);
            }
        }
    }

    const float inv = 1.f / l_r;
    const size_t obase = ((size_t)(b * SEQ) + q0 + fm) * D_MODEL + h * HEAD_DIM;
    #pragma unroll
    for (int dn = 0; dn < 4; ++dn) {
        union { bf16 s[4]; bf16x4 v4; } ov;
        #pragma unroll
        for (int reg = 0; reg < 4; ++reg) ov.s[reg] = f2bf(o[dn][reg] * inv);
        *(bf16x4*)&ctx[obase + dn * 16 + fq * 4] = ov.v4;
    }
}

extern "C" void kernel_launch(void* const* d_in, const int* in_sizes, int n_in,
                              void* d_out, int out_size, void* d_ws, size_t ws_size,
                              hipStream_t stream) {
    const float* x   = (const float*)d_in[0];
    // d_in[1] = attn_mask (int32, causal tril) -- handled analytically
    const float* Wq  = (const float*)d_in[2];
    const float* bq  = (const float*)d_in[3];
    const float* Wk  = (const float*)d_in[4];
    const float* bk  = (const float*)d_in[5];
    const float* Wv  = (const float*)d_in[6];
    const float* bv  = (const float*)d_in[7];
    const float* Wo  = (const float*)d_in[8];
    const float* bo  = (const float*)d_in[9];
    const float* W1  = (const float*)d_in[10];
    const float* b1  = (const float*)d_in[11];
    const float* W2  = (const float*)d_in[12];
    const float* b2  = (const float*)d_in[13];
    const float* g1  = (const float*)d_in[14];
    const float* be1 = (const float*)d_in[15];
    const float* g2  = (const float*)d_in[16];
    const float* be2 = (const float*)d_in[17];
    float* out = (float*)d_out;

    const size_t MB = 1024 * 1024;
    char* ws = (char*)d_ws;
    bf16* xn1 = (bf16*)(ws);             //  0.. 8MB (reused as xn2)
    bf16* xn2 = xn1;
    float* x2 = out;

    ln_kernel<<<ROWS, 256, 0, stream>>>(x, g1, be1, xn1);

    if (ws_size >= 64 * MB) {
        // ws fast-path layout:
        //  8..32MB qkv fused [4096][3072]; 32..40MB ctx; hB 8..40MB (reuses both)
        // 40..46 wqkv; 46..48 wob; 48..56 w1b; 56..64 w2b
        bf16* qkv  = (bf16*)(ws + 8 * MB);
        bf16* ctx  = (bf16*)(ws + 32 * MB);
        bf16* hB   = (bf16*)(ws + 8 * MB);
        bf16* wqkv = (bf16*)(ws + 40 * MB);
        bf16* wob  = (bf16*)(ws + 46 * MB);
        bf16* w1b  = (bf16*)(ws + 48 * MB);
        bf16* w2b  = (bf16*)(ws + 56 * MB);
        const int nD = D_MODEL * D_MODEL;    // 1M
        const int nF = D_MODEL * FF_DIM;     // 4M
        cvt_kernel<<<nD / 2048, 256, 0, stream>>>(Wq, wqkv, nD);
        cvt_kernel<<<nD / 2048, 256, 0, stream>>>(Wk, wqkv + nD, nD);
        cvt_kernel<<<nD / 2048, 256, 0, stream>>>(Wv, wqkv + 2 * nD, nD);
        cvt_kernel<<<nD / 2048, 256, 0, stream>>>(Wo, wob, nD);
        cvt_kernel<<<nF / 2048, 256, 0, stream>>>(W1, w1b, nF);
        cvt_kernel<<<nF / 2048, 256, 0, stream>>>(W2, w2b, nF);

        gemm_qkv<<<dim3(3 * D_MODEL / 64, ROWS / 128), 256, 0, stream>>>(
            xn1, wqkv, bq, bk, bv, qkv);
        attn_mfma<<<dim3(BATCH * N_HEADS, SEQ / 64), 256, 0, stream>>>(
            qkv, qkv + D_MODEL, qkv + 2 * D_MODEL, 3 * D_MODEL, ctx);
        gemm_bb<EPI_RES, 64, float><<<dim3(D_MODEL / 64, ROWS / 128), 256, 0, stream>>>(
            ctx, wob, bo, x, x2, ROWS, D_MODEL, D_MODEL);
        ln_kernel<<<ROWS, 256, 0, stream>>>(x2, g2, be2, xn2);
        gemm_bb<EPI_GELU, 128, bf16><<<dim3(FF_DIM / 128, ROWS / 128), 256, 0, stream>>>(
            xn2, w1b, b1, nullptr, hB, ROWS, FF_DIM, D_MODEL);
        gemm_bb<EPI_RES, 64, float><<<dim3(D_MODEL / 64, ROWS / 128), 256, 0, stream>>>(
            hB, w2b, b2, x2, out, ROWS, D_MODEL, FF_DIM);
    } else {
        // fallback: f32-weight GEMMs, separate q/k/v buffers (stride D_MODEL)
        bf16* qB  = (bf16*)(ws + 8 * MB);
        bf16* kB  = (bf16*)(ws + 16 * MB);
        bf16* vB  = (bf16*)(ws + 24 * MB);
        bf16* ctx = (bf16*)(ws + 32 * MB);
        bf16* hB  = (bf16*)(ws + 8 * MB);
        gemm_nt<EPI_BIAS, bf16><<<dim3(D_MODEL / 128, ROWS / 128), 256, 0, stream>>>(
            xn1, Wq, bq, nullptr, qB, ROWS, D_MODEL, D_MODEL);
        gemm_nt<EPI_BIAS, bf16><<<dim3(D_MODEL / 128, ROWS / 128), 256, 0, stream>>>(
            xn1, Wk, bk, nullptr, kB, ROWS, D_MODEL, D_MODEL);
        gemm_nt<EPI_BIAS, bf16><<<dim3(D_MODEL / 128, ROWS / 128), 256, 0, stream>>>(
            xn1, Wv, bv, nullptr, vB, ROWS, D_MODEL, D_MODEL);
        attn_mfma<<<dim3(BATCH * N_HEADS, SEQ / 64), 256, 0, stream>>>(
            qB, kB, vB, D_MODEL, ctx);
        gemm_nt<EPI_RES, float><<<dim3(D_MODEL / 128, ROWS / 128), 256, 0, stream>>>(
            ctx, Wo, bo, x, x2, ROWS, D_MODEL, D_MODEL);
        ln_kernel<<<ROWS, 256, 0, stream>>>(x2, g2, be2, xn2);
        gemm_nt<EPI_GELU, bf16><<<dim3(FF_DIM / 128, ROWS / 128), 256, 0, stream>>>(
            xn2, W1, b1, nullptr, hB, ROWS, FF_DIM, D_MODEL);
        gemm_nt<EPI_RES, float><<<dim3(D_MODEL / 128, ROWS / 128), 256, 0, stream>>>(
            hB, W2, b2, x2, out, ROWS, D_MODEL, FF_DIM);
    }
}

// Round 7
// 386.623 us; speedup vs baseline: 2.6588x; 1.1662x over previous
//
#include <hip/hip_runtime.h>
#include <hip/hip_bf16.h>
#include <math.h>

#define D_MODEL 1024
#define N_HEADS 16
#define HEAD_DIM 64
#define FF_DIM 4096
#define BATCH 2
#define SEQ 2048
#define ROWS (BATCH*SEQ)  // 4096

typedef __hip_bfloat16 bf16;
typedef short bf16x8 __attribute__((ext_vector_type(8)));
typedef short bf16x4 __attribute__((ext_vector_type(4)));
typedef float f32x4 __attribute__((ext_vector_type(4)));

__device__ __forceinline__ float bf2f(bf16 x) { return __bfloat162float(x); }
__device__ __forceinline__ bf16 f2bf(float x) { return __float2bfloat16(x); }

__device__ __forceinline__ void glds16(const bf16* g, bf16* l) {
    __builtin_amdgcn_global_load_lds(
        (const __attribute__((address_space(1))) void*)g,
        (__attribute__((address_space(3))) void*)l,
        16, 0, 0);
}

// ---------------- fused f32 -> bf16 weight conversion (all weights, 1 launch) ------
__device__ __forceinline__ void cvt2048(const float* __restrict__ s,
                                        bf16* __restrict__ d, int blk) {
    const int i = blk * 2048 + threadIdx.x * 8;
    const float4 a = *(const float4*)(s + i);
    const float4 b = *(const float4*)(s + i + 4);
    union { bf16 q[8]; bf16x8 v; } u;
    u.q[0] = f2bf(a.x); u.q[1] = f2bf(a.y); u.q[2] = f2bf(a.z); u.q[3] = f2bf(a.w);
    u.q[4] = f2bf(b.x); u.q[5] = f2bf(b.y); u.q[6] = f2bf(b.z); u.q[7] = f2bf(b.w);
    *(bf16x8*)(d + i) = u.v;
}

__global__ __launch_bounds__(256) void cvtall_kernel(
    const float* __restrict__ Wq, const float* __restrict__ Wk,
    const float* __restrict__ Wv, const float* __restrict__ Wo,
    const float* __restrict__ W1, const float* __restrict__ W2,
    bf16* __restrict__ wqkv, bf16* __restrict__ wob,
    bf16* __restrict__ w1b, bf16* __restrict__ w2b)
{
    const int blk = blockIdx.x;
    const int nD = D_MODEL * D_MODEL;           // 1M elems = 512 blocks
    if      (blk < 512)  cvt2048(Wq, wqkv,          blk);
    else if (blk < 1024) cvt2048(Wk, wqkv + nD,     blk - 512);
    else if (blk < 1536) cvt2048(Wv, wqkv + 2 * nD, blk - 1024);
    else if (blk < 2048) cvt2048(Wo, wob,           blk - 1536);
    else if (blk < 4096) cvt2048(W1, w1b,           blk - 2048);
    else                 cvt2048(W2, w2b,           blk - 4096);
}

// ---------------- LayerNorm: f32 in -> bf16 out (one block per row) ----------------
__global__ __launch_bounds__(256) void ln_kernel(
    const float* __restrict__ x, const float* __restrict__ gamma,
    const float* __restrict__ beta, bf16* __restrict__ out)
{
    const int row = blockIdx.x;
    const int t = threadIdx.x;
    const float* xr = x + (size_t)row * D_MODEL;
    const float4 xv = *(const float4*)(xr + t * 4);
    float s  = xv.x + xv.y + xv.z + xv.w;
    float ss = xv.x * xv.x + xv.y * xv.y + xv.z * xv.z + xv.w * xv.w;
    #pragma unroll
    for (int o = 32; o > 0; o >>= 1) {
        s  += __shfl_down(s, o);
        ss += __shfl_down(ss, o);
    }
    __shared__ float ps[4], pss[4];
    const int w = t >> 6;
    if ((t & 63) == 0) { ps[w] = s; pss[w] = ss; }
    __syncthreads();
    if (t == 0) {
        ps[0]  = ps[0] + ps[1] + ps[2] + ps[3];
        pss[0] = pss[0] + pss[1] + pss[2] + pss[3];
    }
    __syncthreads();
    s = ps[0]; ss = pss[0];
    const float mu = s * (1.f / D_MODEL);
    float var = ss * (1.f / D_MODEL) - mu * mu;
    var = var < 0.f ? 0.f : var;
    const float rinv = rsqrtf(var + 1e-5f);
    const float4 gv = *(const float4*)(gamma + t * 4);
    const float4 bv = *(const float4*)(beta + t * 4);
    bf16* orow = out + (size_t)row * D_MODEL + t * 4;
    orow[0] = f2bf((xv.x - mu) * rinv * gv.x + bv.x);
    orow[1] = f2bf((xv.y - mu) * rinv * gv.y + bv.y);
    orow[2] = f2bf((xv.z - mu) * rinv * gv.z + bv.z);
    orow[3] = f2bf((xv.w - mu) * rinv * gv.w + bv.w);
}

#define EPI_BIAS 0
#define EPI_GELU 1
#define EPI_RES  2

// ------- bf16 GEMM: C[M,N] = A[M,K] @ Wb[N,K]^T + bias, epilogue -------
// 128 x TN tile, BK=64 via dual 32-k planes (keeps glds16 contiguity + m97 bank pattern).
// TRIPLE: bias selected per 1024-col segment (fused QKV).
template <int EPI, int TN, typename CT, bool TRIPLE>
__global__ __launch_bounds__(256) void gemm_bb(
    const bf16* __restrict__ A, const bf16* __restrict__ W,
    const float* __restrict__ b0, const float* __restrict__ b1p,
    const float* __restrict__ b2p, const float* __restrict__ res,
    CT* __restrict__ C, int M, int N, int K)
{
    __shared__ bf16 As[2][128 * 32];
    __shared__ bf16 Ws[2][TN * 32];
    const int tid  = threadIdx.x;
    const int wave = tid >> 6;
    const int lane = tid & 63;
    const int mBlock = blockIdx.y * 128;
    const int nBlock = blockIdx.x * TN;

    const int sRow = lane >> 2;        // 0..15
    const int sCol = (lane & 3) * 8;   // 0,8,16,24

    // A: wave covers rows [wave*32, +32) as two 16-row chunks
    const bf16* aS0 = A + (size_t)(mBlock + wave * 32 + sRow) * K + sCol;
    const bf16* aS1 = aS0 + (size_t)16 * K;
    bf16* aD0[2] = { &As[0][(wave * 32) * 32],      &As[1][(wave * 32) * 32] };
    bf16* aD1[2] = { &As[0][(wave * 32 + 16) * 32], &As[1][(wave * 32 + 16) * 32] };

    // W: TN==128 -> 32 rows/wave (2 chunks); TN==64 -> 16 rows/wave (1 chunk)
    const int wRowBase = (TN == 128) ? wave * 32 : wave * 16;
    const bf16* wS0 = W + (size_t)(nBlock + wRowBase + sRow) * K + sCol;
    const bf16* wS1 = wS0 + (size_t)16 * K;
    bf16* wD0[2] = { &Ws[0][wRowBase * 32], &Ws[1][wRowBase * 32] };
    bf16* wD1[2] = { &Ws[0][(wRowBase + 16) * 32], &Ws[1][(wRowBase + 16) * 32] };

    constexpr int WN = (TN == 128) ? 64 : 32;
    constexpr int NJ = WN / 16;
    const int wm = (wave >> 1) * 64;
    const int wn = (wave & 1) * WN;
    const int fRow = lane & 15;
    const int fK   = (lane >> 4) * 8;

    f32x4 acc[4][NJ];
    #pragma unroll
    for (int i = 0; i < 4; ++i)
        #pragma unroll
        for (int j = 0; j < NJ; ++j) {
            f32x4 z = {0.f, 0.f, 0.f, 0.f};
            acc[i][j] = z;
        }

    for (int k0 = 0; k0 < K; k0 += 64) {
        #pragma unroll
        for (int p = 0; p < 2; ++p) {
            glds16(aS0 + k0 + p * 32, aD0[p]);
            glds16(aS1 + k0 + p * 32, aD1[p]);
            glds16(wS0 + k0 + p * 32, wD0[p]);
            if (TN == 128) glds16(wS1 + k0 + p * 32, wD1[p]);
        }
        __syncthreads();   // DMA drained + barrier

        bf16x8 af[4][2], wf[NJ][2];
        #pragma unroll
        for (int ti = 0; ti < 4; ++ti) {
            af[ti][0] = *(const bf16x8*)&As[0][(wm + ti * 16 + fRow) * 32 + fK];
            af[ti][1] = *(const bf16x8*)&As[1][(wm + ti * 16 + fRow) * 32 + fK];
        }
        #pragma unroll
        for (int tj = 0; tj < NJ; ++tj) {
            wf[tj][0] = *(const bf16x8*)&Ws[0][(wn + tj * 16 + fRow) * 32 + fK];
            wf[tj][1] = *(const bf16x8*)&Ws[1][(wn + tj * 16 + fRow) * 32 + fK];
        }
        #pragma unroll
        for (int ti = 0; ti < 4; ++ti)
            #pragma unroll
            for (int tj = 0; tj < NJ; ++tj) {
                acc[ti][tj] = __builtin_amdgcn_mfma_f32_16x16x32_bf16(
                    af[ti][0], wf[tj][0], acc[ti][tj], 0, 0, 0);
                acc[ti][tj] = __builtin_amdgcn_mfma_f32_16x16x32_bf16(
                    af[ti][1], wf[tj][1], acc[ti][tj], 0, 0, 0);
            }
        __syncthreads();
    }

    const int lr = (lane >> 4) * 4;
    const int lc = lane & 15;
    #pragma unroll
    for (int ti = 0; ti < 4; ++ti) {
        #pragma unroll
        for (int tj = 0; tj < NJ; ++tj) {
            const int n = nBlock + wn + tj * 16 + lc;
            float bv;
            if (TRIPLE) {
                const float* bp = (n < 1024) ? b0 : (n < 2048) ? b1p : b2p;
                bv = bp[n & 1023];
            } else {
                bv = b0[n];
            }
            #pragma unroll
            for (int rr = 0; rr < 4; ++rr) {
                const int m = mBlock + wm + ti * 16 + lr + rr;
                float vv = acc[ti][tj][rr] + bv;
                if (EPI == EPI_GELU)
                    vv = 0.5f * vv * (1.f + erff(vv * 0.70710678118654752f));
                if (EPI == EPI_RES)
                    vv += res[(size_t)m * N + n];
                if constexpr (sizeof(CT) == 2)
                    C[(size_t)m * N + n] = f2bf(vv);
                else
                    C[(size_t)m * N + n] = vv;
            }
        }
    }
}

// ------- f32-weight GEMM (fallback path, proven) -------
__device__ __forceinline__ bf16x8 cvt8(float a, float b, float c, float d,
                                       float e, float f, float g, float h) {
    union { bf16 s[8]; bf16x8 v; } u;
    u.s[0] = f2bf(a); u.s[1] = f2bf(b); u.s[2] = f2bf(c); u.s[3] = f2bf(d);
    u.s[4] = f2bf(e); u.s[5] = f2bf(f); u.s[6] = f2bf(g); u.s[7] = f2bf(h);
    return u.v;
}

template <int EPI, typename CT>
__global__ __launch_bounds__(256, 2) void gemm_nt(
    const bf16* __restrict__ A, const float* __restrict__ W,
    const float* __restrict__ bias, const float* __restrict__ res,
    CT* __restrict__ C, int M, int N, int K)
{
    __shared__ bf16 As[128 * 32];
    __shared__ bf16 Ws[128 * 32];
    const int tid  = threadIdx.x;
    const int wave = tid >> 6;
    const int lane = tid & 63;
    const int mBlock = blockIdx.y * 128;
    const int nBlock = blockIdx.x * 128;
    const int r0 = tid >> 2;
    const int c0 = (tid & 3) * 8;
    const bf16*  aP0 = A + (size_t)(mBlock + r0) * K + c0;
    const bf16*  aP1 = A + (size_t)(mBlock + 64 + r0) * K + c0;
    const float* wP0 = W + (size_t)(nBlock + r0) * K + c0;
    const float* wP1 = W + (size_t)(nBlock + 64 + r0) * K + c0;
    const int wm = (wave >> 1) * 64;
    const int wn = (wave & 1) * 64;
    const int fRow = lane & 15;
    const int fK   = (lane >> 4) * 8;
    f32x4 acc[4][4];
    #pragma unroll
    for (int i = 0; i < 4; ++i)
        #pragma unroll
        for (int j = 0; j < 4; ++j) {
            f32x4 z = {0.f, 0.f, 0.f, 0.f};
            acc[i][j] = z;
        }
    for (int k0 = 0; k0 < K; k0 += 32) {
        const bf16x8 a0 = *(const bf16x8*)(aP0 + k0);
        const bf16x8 a1 = *(const bf16x8*)(aP1 + k0);
        const float4 wa0 = *(const float4*)(wP0 + k0);
        const float4 wa1 = *(const float4*)(wP0 + k0 + 4);
        const float4 wb0 = *(const float4*)(wP1 + k0);
        const float4 wb1 = *(const float4*)(wP1 + k0 + 4);
        const bf16x8 w0 = cvt8(wa0.x, wa0.y, wa0.z, wa0.w, wa1.x, wa1.y, wa1.z, wa1.w);
        const bf16x8 w1 = cvt8(wb0.x, wb0.y, wb0.z, wb0.w, wb1.x, wb1.y, wb1.z, wb1.w);
        __syncthreads();
        *(bf16x8*)&As[r0 * 32 + c0]        = a0;
        *(bf16x8*)&As[(64 + r0) * 32 + c0] = a1;
        *(bf16x8*)&Ws[r0 * 32 + c0]        = w0;
        *(bf16x8*)&Ws[(64 + r0) * 32 + c0] = w1;
        __syncthreads();
        bf16x8 af[4], wf[4];
        #pragma unroll
        for (int ti = 0; ti < 4; ++ti)
            af[ti] = *(const bf16x8*)&As[(wm + ti * 16 + fRow) * 32 + fK];
        #pragma unroll
        for (int tj = 0; tj < 4; ++tj)
            wf[tj] = *(const bf16x8*)&Ws[(wn + tj * 16 + fRow) * 32 + fK];
        #pragma unroll
        for (int ti = 0; ti < 4; ++ti)
            #pragma unroll
            for (int tj = 0; tj < 4; ++tj)
                acc[ti][tj] = __builtin_amdgcn_mfma_f32_16x16x32_bf16(
                    af[ti], wf[tj], acc[ti][tj], 0, 0, 0);
    }
    const int lr = (lane >> 4) * 4;
    const int lc = lane & 15;
    #pragma unroll
    for (int ti = 0; ti < 4; ++ti) {
        #pragma unroll
        for (int tj = 0; tj < 4; ++tj) {
            const int n = nBlock + wn + tj * 16 + lc;
            const float bv = bias[n];
            #pragma unroll
            for (int rr = 0; rr < 4; ++rr) {
                const int m = mBlock + wm + ti * 16 + lr + rr;
                float vv = acc[ti][tj][rr] + bv;
                if (EPI == EPI_GELU)
                    vv = 0.5f * vv * (1.f + erff(vv * 0.70710678118654752f));
                if (EPI == EPI_RES)
                    vv += res[(size_t)m * N + n];
                if constexpr (sizeof(CT) == 2)
                    C[(size_t)m * N + n] = f2bf(vv);
                else
                    C[(size_t)m * N + n] = vv;
            }
        }
    }
}

// ---------------- MFMA flash attention, S^T formulation, 64-key tiles ----------------
// grid (B*N_HEADS, SEQ/64), block 256 = 4 waves; wave w owns q rows [qb*64+w*16, +16).
__global__ __launch_bounds__(256) void attn_mfma(
    const bf16* __restrict__ q, const bf16* __restrict__ k,
    const bf16* __restrict__ v, int qkvStride, bf16* __restrict__ ctx)
{
    const int bh = blockIdx.x;
    const int b = bh >> 4, h = bh & 15;
    const int qb = (gridDim.y - 1) - blockIdx.y;  // descending: big blocks first
    const int tid = threadIdx.x;
    const int wave = tid >> 6, lane = tid & 63;
    const int fm = lane & 15;
    const int fq = lane >> 4;

    __shared__ bf16 Ks[2][64][40];  // [k-half][key][d%32], 80B rows
    __shared__ bf16 Vts[64][72];    // [d][key 0..63], 144B rows
    __shared__ bf16 Ps[4][16][72];  // per-wave P^T: [q][key 0..63]

    const int q0 = qb * 64 + wave * 16;
    const size_t qrow = ((size_t)(b * SEQ) + q0 + fm) * qkvStride + h * HEAD_DIM;
    const bf16x8 Qf0 = *(const bf16x8*)&q[qrow + fq * 8];
    const bf16x8 Qf1 = *(const bf16x8*)&q[qrow + 32 + fq * 8];

    f32x4 o[4];   // o[dn][reg] = O^T[d = dn*16 + fq*4 + reg][q = q0+fm]
    #pragma unroll
    for (int i = 0; i < 4; ++i) { f32x4 z = {0.f,0.f,0.f,0.f}; o[i] = z; }
    float m_r = -INFINITY, l_r = 0.f;

    // staging maps
    const int sr = tid >> 2;      // K: key 0..63
    const int sc = tid & 3;       // K: 8-elem d-chunk within half
    const int vp = tid & 31;      // V: key pair (keys 2vp, 2vp+1)
    const int vdg = tid >> 5;     // V: d-octet 0..7

    const int nKB = qb + 1;
    for (int kb = 0; kb < nKB; ++kb) {
        const int j0 = kb * 64;
        const size_t kbase = ((size_t)(b * SEQ) + j0 + sr) * qkvStride + h * HEAD_DIM + sc * 8;
        const bf16x8 kv0 = *(const bf16x8*)&k[kbase];
        const bf16x8 kv1 = *(const bf16x8*)&k[kbase + 32];
        const size_t vbase = ((size_t)(b * SEQ) + j0 + 2 * vp) * qkvStride + h * HEAD_DIM + vdg * 8;
        const bf16x8 va = *(const bf16x8*)&v[vbase];
        const bf16x8 vb = *(const bf16x8*)&v[vbase + qkvStride];
        __syncthreads();
        *(bf16x8*)&Ks[0][sr][sc * 8] = kv0;
        *(bf16x8*)&Ks[1][sr][sc * 8] = kv1;
        #pragma unroll
        for (int i = 0; i < 8; ++i) {
            const unsigned packed = (unsigned)(unsigned short)va[i] |
                                    ((unsigned)(unsigned short)vb[i] << 16);
            *(unsigned*)&Vts[vdg * 8 + i][2 * vp] = packed;
        }
        __syncthreads();

        // --- S^T = K·Q^T : rows=keys (n0+fq*4+reg), cols=q (fm) ---
        float p[4][4];
        #pragma unroll
        for (int sub = 0; sub < 4; ++sub) {
            const int n0 = sub * 16;
            if (j0 + n0 <= q0 + 15) {
                const bf16x8 kf0 = *(const bf16x8*)&Ks[0][n0 + fm][fq * 8];
                const bf16x8 kf1 = *(const bf16x8*)&Ks[1][n0 + fm][fq * 8];
                f32x4 acc = {0.f, 0.f, 0.f, 0.f};
                acc = __builtin_amdgcn_mfma_f32_16x16x32_bf16(kf0, Qf0, acc, 0, 0, 0);
                acc = __builtin_amdgcn_mfma_f32_16x16x32_bf16(kf1, Qf1, acc, 0, 0, 0);
                #pragma unroll
                for (int reg = 0; reg < 4; ++reg)
                    p[sub][reg] = acc[reg] * 0.125f;
                if (j0 + n0 + 15 > q0) {
                    #pragma unroll
                    for (int reg = 0; reg < 4; ++reg)
                        if (j0 + n0 + fq * 4 + reg > q0 + fm) p[sub][reg] = -INFINITY;
                }
            } else {
                #pragma unroll
                for (int reg = 0; reg < 4; ++reg) p[sub][reg] = -INFINITY;
            }
        }

        // --- online softmax, per lane (q = q0+fm); cross-quad via 2 shfls ---
        float mx = p[0][0];
        #pragma unroll
        for (int sub = 0; sub < 4; ++sub)
            #pragma unroll
            for (int reg = 0; reg < 4; ++reg) mx = fmaxf(mx, p[sub][reg]);
        mx = fmaxf(mx, __shfl_xor(mx, 16));
        mx = fmaxf(mx, __shfl_xor(mx, 32));
        const float mnew = fmaxf(m_r, mx);
        float sum = 0.f;
        #pragma unroll
        for (int sub = 0; sub < 4; ++sub)
            #pragma unroll
            for (int reg = 0; reg < 4; ++reg) {
                const float e = __expf(p[sub][reg] - mnew);
                p[sub][reg] = e;
                sum += e;
            }
        sum += __shfl_xor(sum, 16);
        sum += __shfl_xor(sum, 32);
        const float alpha = __expf(m_r - mnew);
        m_r = mnew;
        l_r = l_r * alpha + sum;
        #pragma unroll
        for (int dn = 0; dn < 4; ++dn)
            #pragma unroll
            for (int rr = 0; rr < 4; ++rr) o[dn][rr] *= alpha;

        // write P^T: lane holds keys {n0 + fq*4 + reg} for q=fm
        #pragma unroll
        for (int sub = 0; sub < 4; ++sub) {
            union { unsigned u; bf16 s[2]; } pk0, pk1;
            pk0.s[0] = f2bf(p[sub][0]); pk0.s[1] = f2bf(p[sub][1]);
            pk1.s[0] = f2bf(p[sub][2]); pk1.s[1] = f2bf(p[sub][3]);
            *(unsigned*)&Ps[wave][fm][sub * 16 + fq * 4]     = pk0.u;
            *(unsigned*)&Ps[wave][fm][sub * 16 + fq * 4 + 2] = pk1.u;
        }

        // --- O^T += V·P^T (keys 0..31 then 32..63) ---
        const bf16x8 pf0 = *(const bf16x8*)&Ps[wave][fm][fq * 8];
        const bf16x8 pf1 = *(const bf16x8*)&Ps[wave][fm][32 + fq * 8];
        #pragma unroll
        for (int dn = 0; dn < 4; ++dn) {
            const bf16x8 vf0 = *(const bf16x8*)&Vts[dn * 16 + fm][fq * 8];
            const bf16x8 vf1 = *(const bf16x8*)&Vts[dn * 16 + fm][32 + fq * 8];
            o[dn] = __builtin_amdgcn_mfma_f32_16x16x32_bf16(vf0, pf0, o[dn], 0, 0, 0);
            o[dn] = __builtin_amdgcn_mfma_f32_16x16x32_bf16(vf1, pf1, o[dn], 0, 0, 0);
        }
    }

    const float inv = 1.f / l_r;
    const size_t obase = ((size_t)(b * SEQ) + q0 + fm) * D_MODEL + h * HEAD_DIM;
    #pragma unroll
    for (int dn = 0; dn < 4; ++dn) {
        union { bf16 s[4]; bf16x4 v4; } ov;
        #pragma unroll
        for (int reg = 0; reg < 4; ++reg) ov.s[reg] = f2bf(o[dn][reg] * inv);
        *(bf16x4*)&ctx[obase + dn * 16 + fq * 4] = ov.v4;
    }
}

extern "C" void kernel_launch(void* const* d_in, const int* in_sizes, int n_in,
                              void* d_out, int out_size, void* d_ws, size_t ws_size,
                              hipStream_t stream) {
    const float* x   = (const float*)d_in[0];
    // d_in[1] = attn_mask (int32, causal tril) -- handled analytically
    const float* Wq  = (const float*)d_in[2];
    const float* bq  = (const float*)d_in[3];
    const float* Wk  = (const float*)d_in[4];
    const float* bk  = (const float*)d_in[5];
    const float* Wv  = (const float*)d_in[6];
    const float* bv  = (const float*)d_in[7];
    const float* Wo  = (const float*)d_in[8];
    const float* bo  = (const float*)d_in[9];
    const float* W1  = (const float*)d_in[10];
    const float* b1  = (const float*)d_in[11];
    const float* W2  = (const float*)d_in[12];
    const float* b2  = (const float*)d_in[13];
    const float* g1  = (const float*)d_in[14];
    const float* be1 = (const float*)d_in[15];
    const float* g2  = (const float*)d_in[16];
    const float* be2 = (const float*)d_in[17];
    float* out = (float*)d_out;

    const size_t MB = 1024 * 1024;
    char* ws = (char*)d_ws;
    bf16* xn1 = (bf16*)(ws);             //  0.. 8MB (reused as xn2)
    bf16* xn2 = xn1;
    float* x2 = out;

    ln_kernel<<<ROWS, 256, 0, stream>>>(x, g1, be1, xn1);

    if (ws_size >= 64 * MB) {
        //  8..32MB qkv [4096][3072]; 32..40MB ctx; hB 8..40MB (reuses both)
        // 40..46 wqkv; 46..48 wob; 48..56 w1b; 56..64 w2b
        bf16* qkv  = (bf16*)(ws + 8 * MB);
        bf16* ctx  = (bf16*)(ws + 32 * MB);
        bf16* hB   = (bf16*)(ws + 8 * MB);
        bf16* wqkv = (bf16*)(ws + 40 * MB);
        bf16* wob  = (bf16*)(ws + 46 * MB);
        bf16* w1b  = (bf16*)(ws + 48 * MB);
        bf16* w2b  = (bf16*)(ws + 56 * MB);
        cvtall_kernel<<<6144, 256, 0, stream>>>(Wq, Wk, Wv, Wo, W1, W2,
                                                wqkv, wob, w1b, w2b);

        gemm_bb<EPI_BIAS, 64, bf16, true><<<dim3(3 * D_MODEL / 64, ROWS / 128), 256, 0, stream>>>(
            xn1, wqkv, bq, bk, bv, nullptr, qkv, ROWS, 3 * D_MODEL, D_MODEL);
        attn_mfma<<<dim3(BATCH * N_HEADS, SEQ / 64), 256, 0, stream>>>(
            qkv, qkv + D_MODEL, qkv + 2 * D_MODEL, 3 * D_MODEL, ctx);
        gemm_bb<EPI_RES, 64, float, false><<<dim3(D_MODEL / 64, ROWS / 128), 256, 0, stream>>>(
            ctx, wob, bo, nullptr, nullptr, x, x2, ROWS, D_MODEL, D_MODEL);
        ln_kernel<<<ROWS, 256, 0, stream>>>(x2, g2, be2, xn2);
        gemm_bb<EPI_GELU, 128, bf16, false><<<dim3(FF_DIM / 128, ROWS / 128), 256, 0, stream>>>(
            xn2, w1b, b1, nullptr, nullptr, nullptr, hB, ROWS, FF_DIM, D_MODEL);
        gemm_bb<EPI_RES, 64, float, false><<<dim3(D_MODEL / 64, ROWS / 128), 256, 0, stream>>>(
            hB, w2b, b2, nullptr, nullptr, x2, out, ROWS, D_MODEL, FF_DIM);
    } else {
        // fallback: f32-weight GEMMs, separate q/k/v buffers (stride D_MODEL)
        bf16* qB  = (bf16*)(ws + 8 * MB);
        bf16* kB  = (bf16*)(ws + 16 * MB);
        bf16* vB  = (bf16*)(ws + 24 * MB);
        bf16* ctx = (bf16*)(ws + 32 * MB);
        bf16* hB  = (bf16*)(ws + 8 * MB);
        gemm_nt<EPI_BIAS, bf16><<<dim3(D_MODEL / 128, ROWS / 128), 256, 0, stream>>>(
            xn1, Wq, bq, nullptr, qB, ROWS, D_MODEL, D_MODEL);
        gemm_nt<EPI_BIAS, bf16><<<dim3(D_MODEL / 128, ROWS / 128), 256, 0, stream>>>(
            xn1, Wk, bk, nullptr, kB, ROWS, D_MODEL, D_MODEL);
        gemm_nt<EPI_BIAS, bf16><<<dim3(D_MODEL / 128, ROWS / 128), 256, 0, stream>>>(
            xn1, Wv, bv, nullptr, vB, ROWS, D_MODEL, D_MODEL);
        attn_mfma<<<dim3(BATCH * N_HEADS, SEQ / 64), 256, 0, stream>>>(
            qB, kB, vB, D_MODEL, ctx);
        gemm_nt<EPI_RES, float><<<dim3(D_MODEL / 128, ROWS / 128), 256, 0, stream>>>(
            ctx, Wo, bo, x, x2, ROWS, D_MODEL, D_MODEL);
        ln_kernel<<<ROWS, 256, 0, stream>>>(x2, g2, be2, xn2);
        gemm_nt<EPI_GELU, bf16><<<dim3(FF_DIM / 128, ROWS / 128), 256, 0, stream>>>(
            xn2, W1, b1, nullptr, hB, ROWS, FF_DIM, D_MODEL);
        gemm_nt<EPI_RES, float><<<dim3(D_MODEL / 128, ROWS / 128), 256, 0, stream>>>(
            hB, W2, b2, x2, out, ROWS, D_MODEL, FF_DIM);
    }
}